// Round 2
// baseline (2343.924 us; speedup 1.0000x reference)
//
#include <hip/hip_runtime.h>
#include <math.h>

// ---- problem constants ----
#define NC   384
#define NHQ  8
#define NHKV 2
#define NHD  48
#define NR   4
#define NEXP 4
#define NB   4
#define NT   2048
#define NTOKENS 8192          // NB*NT
#define NCAP 2560             // ceil(1.25*8192/4)
#define NFF  1536             // 4*NC
#define NQKV 576              // 384+96+96
#define LORA_SCALE 0.25f

// ---- ws layout (float offsets) ----
#define OFF_H     ((size_t)0)
#define OFF_Q     ((size_t)3145728)
#define OFF_K     ((size_t)6291456)
#define OFF_V     ((size_t)7077888)
#define OFF_O     ((size_t)7864320)
#define OFF_FLAT  ((size_t)11010048)
#define OFF_WPK   ((size_t)14155776)
#define OFF_BPK   ((size_t)14376960)
#define OFF_PROBS ((size_t)14379264)
#define OFF_T1V   ((size_t)14412032)
#define OFF_T1I   ((size_t)14420224)
#define OFF_SLOT  ((size_t)14428416)

// ============================================================
// LayerNorm: one wave per row, 4 rows/block
// ============================================================
__global__ __launch_bounds__(256) void ln_kernel(const float* __restrict__ x,
    const float* __restrict__ g, const float* __restrict__ bb,
    float* __restrict__ out) {
  int row = blockIdx.x * 4 + (threadIdx.x >> 6);
  int lane = threadIdx.x & 63;
  const float* xr = x + (size_t)row * NC;
  float v0[6];
  float s = 0.f;
#pragma unroll
  for (int i = 0; i < 6; i++) { v0[i] = xr[lane + i * 64]; s += v0[i]; }
#pragma unroll
  for (int o = 32; o > 0; o >>= 1) s += __shfl_xor(s, o);
  float mean = s * (1.f / NC);
  float s2 = 0.f;
#pragma unroll
  for (int i = 0; i < 6; i++) { float d = v0[i] - mean; s2 += d * d; }
#pragma unroll
  for (int o = 32; o > 0; o >>= 1) s2 += __shfl_xor(s2, o);
  float rstd = rsqrtf(s2 * (1.f / NC) + 1e-5f);
  float* orow = out + (size_t)row * NC;
#pragma unroll
  for (int i = 0; i < 6; i++) {
    int c = lane + i * 64;
    orow[c] = (v0[i] - mean) * rstd * g[c] + bb[c];
  }
}

// ============================================================
// Pack Wq|Wk|Wv -> (384,576), Bq|Bk|Bv[aid] -> (576,4); init slot_token=-1
// ============================================================
__global__ void pack_kernel(const int* __restrict__ aidp,
    const float* __restrict__ Wq, const float* __restrict__ Bq,
    const float* __restrict__ Wk, const float* __restrict__ Bk,
    const float* __restrict__ Wv, const float* __restrict__ Bv,
    float* __restrict__ Wpk, float* __restrict__ Bpk, int* __restrict__ slot_token) {
  int aid = aidp[0];
  int idx = blockIdx.x * 256 + threadIdx.x;
  if (idx < NC * NQKV) {
    int c = idx / NQKV, col = idx % NQKV;
    float w;
    if (col < 384) w = Wq[c * 384 + col];
    else if (col < 480) w = Wk[c * 96 + (col - 384)];
    else w = Wv[c * 96 + (col - 480)];
    Wpk[idx] = w;
  }
  if (idx < NQKV * NR) {
    int col = idx >> 2, r = idx & 3;
    float w;
    if (col < 384) w = Bq[((size_t)aid * 384 + col) * 4 + r];
    else if (col < 480) w = Bk[((size_t)aid * 96 + (col - 384)) * 4 + r];
    else w = Bv[((size_t)aid * 96 + (col - 480)) * 4 + r];
    Bpk[idx] = w;
  }
  if (idx < NEXP * NCAP) slot_token[idx] = -1;
}

// ============================================================
// QKV: h(8192x384) @ Wpk(384x576) + LoRA; scatter to q/k/v (B,H,T,HD)
// ============================================================
__global__ __launch_bounds__(256) void qkv_kernel(const float* __restrict__ h,
    const int* __restrict__ aidp, const float* __restrict__ Wpk, const float* __restrict__ Bpk,
    const float* __restrict__ Aq, const float* __restrict__ Ak, const float* __restrict__ Av,
    float* __restrict__ q, float* __restrict__ k, float* __restrict__ v) {
  __shared__ float ht[16][385];
  __shared__ float tl[16][12];
  int aid = aidp[0];
  int row0 = blockIdx.x * 16;
  int tid = threadIdx.x;
  for (int i = tid; i < 16 * NC; i += 256) ht[i / NC][i % NC] = h[(size_t)row0 * NC + i];
  __syncthreads();
  if (tid < 192) {
    int r = tid / 12, j = tid % 12;
    const float* A = (j < 4) ? Aq : ((j < 8) ? Ak : Av);
    const float* Arow = A + ((size_t)aid * NR + (j & 3)) * NC;
    float s = 0.f;
    for (int c = 0; c < NC; c++) s += ht[r][c] * Arow[c];
    tl[r][j] = s;
  }
  __syncthreads();
  int tx = tid & 63, ty = tid >> 6;
  float acc[4][9];
#pragma unroll
  for (int a = 0; a < 4; a++)
#pragma unroll
    for (int gg = 0; gg < 9; gg++) acc[a][gg] = 0.f;
  for (int c = 0; c < NC; c++) {
    float hv[4];
#pragma unroll
    for (int rr = 0; rr < 4; rr++) hv[rr] = ht[ty + rr * 4][c];
    const float* wrow = Wpk + (size_t)c * NQKV;
#pragma unroll
    for (int gg = 0; gg < 9; gg++) {
      float w = wrow[gg * 64 + tx];
#pragma unroll
      for (int rr = 0; rr < 4; rr++) acc[rr][gg] += hv[rr] * w;
    }
  }
#pragma unroll
  for (int rr = 0; rr < 4; rr++) {
    int rloc = ty + rr * 4;
    int rowg = row0 + rloc;
    int b = rowg >> 11;
    int t = rowg & 2047;
#pragma unroll
    for (int gg = 0; gg < 9; gg++) {
      int col = gg * 64 + tx;
      // rank base: q cols use tl[0..3] (h@Aq), k cols tl[4..7], v cols tl[8..11]
      int rbase = (col < 384) ? 0 : ((col < 480) ? 4 : 8);
      float lsum = 0.f;
#pragma unroll
      for (int r2 = 0; r2 < 4; r2++) lsum += tl[rloc][rbase + r2] * Bpk[col * 4 + r2];
      float val = acc[rr][gg] + LORA_SCALE * lsum;
      if (col < 384) {
        int hh = col / 48, d = col - hh * 48;
        q[(((size_t)b * NHQ + hh) * NT + t) * NHD + d] = val;
      } else if (col < 480) {
        int c2 = col - 384; int hh = c2 / 48, d = c2 - hh * 48;
        k[(((size_t)b * NHKV + hh) * NT + t) * NHD + d] = val;
      } else {
        int c2 = col - 480; int hh = c2 / 48, d = c2 - hh * 48;
        v[(((size_t)b * NHKV + hh) * NT + t) * NHD + d] = val;
      }
    }
  }
}

// ============================================================
// RoPE in place on (BH, T, 48) rows; one thread per (row, pair)
// ============================================================
__global__ void rope_kernel(float* __restrict__ p, int total_pairs) {
  int idx = blockIdx.x * 256 + threadIdx.x;
  if (idx >= total_pairs) return;
  int j = idx % 24;
  int rowt = idx / 24;          // bh*T + t
  int t = rowt & (NT - 1);
  float* a = p + (size_t)rowt * NHD + 2 * j;
  float ex = (float)(2 * j) * (1.f / 48.f);
  float inv = powf(10000.f, -ex);
  float ang = (float)t * inv;
  float sn, cs;
  sincosf(ang, &sn, &cs);
  float e = a[0], o = a[1];
  a[0] = e * cs - o * sn;
  a[1] = e * sn + o * cs;
}

// ============================================================
// Flash-style causal attention, fp32. Q-tile 32, K-tile 32.
// grid (T/32, B*HQ), 256 threads: 8 threads per q-row.
// ============================================================
__global__ __launch_bounds__(256) void attn_kernel(const float* __restrict__ q,
    const float* __restrict__ k, const float* __restrict__ v, float* __restrict__ o) {
  int qt = blockIdx.x;
  int bh = blockIdx.y;
  int b = bh >> 3, hq = bh & 7, hk = hq >> 2;
  const float* qp = q + (((size_t)b * NHQ + hq) * NT + qt * 32) * NHD;
  const float* kp = k + (((size_t)b * NHKV + hk) * NT) * NHD;
  const float* vp = v + (((size_t)b * NHKV + hk) * NT) * NHD;
  __shared__ float Qs[32][49], Ks[32][49], Vs[32][49], Ss[32][33];
  int tid = threadIdx.x;
  for (int i = tid; i < 32 * 48; i += 256) Qs[i / 48][i % 48] = qp[i] * 0.14433756729740643f;
  int qr = tid >> 3, j = tid & 7;
  int qglob = qt * 32 + qr;
  float m = -INFINITY, l = 0.f;
  float acc[6] = {0.f, 0.f, 0.f, 0.f, 0.f, 0.f};
  __syncthreads();
  for (int kt = 0; kt <= qt; kt++) {
    for (int i = tid; i < 32 * 48; i += 256) {
      Ks[i / 48][i % 48] = kp[(size_t)kt * 32 * 48 + i];
      Vs[i / 48][i % 48] = vp[(size_t)kt * 32 * 48 + i];
    }
    __syncthreads();
    float sv[4];
#pragma unroll
    for (int kk = 0; kk < 4; kk++) {
      int kr = j * 4 + kk;
      float s = 0.f;
#pragma unroll 8
      for (int d = 0; d < 48; d++) s += Qs[qr][d] * Ks[kr][d];
      sv[kk] = (kt * 32 + kr <= qglob) ? s : -INFINITY;
    }
    float mx = fmaxf(fmaxf(sv[0], sv[1]), fmaxf(sv[2], sv[3]));
#pragma unroll
    for (int off = 1; off < 8; off <<= 1) mx = fmaxf(mx, __shfl_xor(mx, off));
    float mnew = fmaxf(m, mx);
    float p[4]; float psum = 0.f;
#pragma unroll
    for (int kk = 0; kk < 4; kk++) { p[kk] = expf(sv[kk] - mnew); psum += p[kk]; }
#pragma unroll
    for (int off = 1; off < 8; off <<= 1) psum += __shfl_xor(psum, off);
    float corr = expf(m - mnew);
    l = l * corr + psum;
    m = mnew;
#pragma unroll
    for (int dd = 0; dd < 6; dd++) acc[dd] *= corr;
#pragma unroll
    for (int kk = 0; kk < 4; kk++) Ss[qr][j * 4 + kk] = p[kk];
    __syncthreads();
#pragma unroll 4
    for (int kr = 0; kr < 32; kr++) {
      float pv = Ss[qr][kr];
#pragma unroll
      for (int dd = 0; dd < 6; dd++) acc[dd] += pv * Vs[kr][j * 6 + dd];
    }
    __syncthreads();
  }
  float invl = 1.f / l;
  float* op = o + ((size_t)b * NT + qglob) * NC + hq * 48 + j * 6;
#pragma unroll
  for (int dd = 0; dd < 6; dd++) op[dd] = acc[dd] * invl;
}

// ============================================================
// O-projection + LoRA + residual -> d_out (x2)
// ============================================================
__global__ __launch_bounds__(256) void proj_kernel(const float* __restrict__ o,
    const float* __restrict__ x, const int* __restrict__ aidp,
    const float* __restrict__ Wo, const float* __restrict__ Ao, const float* __restrict__ Bo,
    float* __restrict__ out) {
  __shared__ float ht[16][385];
  __shared__ float tl[16][4];
  int aid = aidp[0];
  int row0 = blockIdx.x * 16;
  int tid = threadIdx.x;
  for (int i = tid; i < 16 * NC; i += 256) ht[i / NC][i % NC] = o[(size_t)row0 * NC + i];
  __syncthreads();
  if (tid < 64) {
    int r = tid >> 2, rr = tid & 3;
    const float* Arow = Ao + ((size_t)aid * NR + rr) * NC;
    float s = 0.f;
    for (int c = 0; c < NC; c++) s += ht[r][c] * Arow[c];
    tl[r][rr] = s;
  }
  __syncthreads();
  int tx = tid & 63, ty = tid >> 6;
  float acc[4][6];
#pragma unroll
  for (int a = 0; a < 4; a++)
#pragma unroll
    for (int gg = 0; gg < 6; gg++) acc[a][gg] = 0.f;
  for (int c = 0; c < NC; c++) {
    float hv[4];
#pragma unroll
    for (int rr = 0; rr < 4; rr++) hv[rr] = ht[ty + rr * 4][c];
    const float* wrow = Wo + (size_t)c * NC;
#pragma unroll
    for (int gg = 0; gg < 6; gg++) {
      float w = wrow[gg * 64 + tx];
#pragma unroll
      for (int rr = 0; rr < 4; rr++) acc[rr][gg] += hv[rr] * w;
    }
  }
#pragma unroll
  for (int rr = 0; rr < 4; rr++) {
    int rloc = ty + rr * 4;
    size_t rowg = row0 + rloc;
#pragma unroll
    for (int gg = 0; gg < 6; gg++) {
      int col = gg * 64 + tx;
      float lsum = 0.f;
#pragma unroll
      for (int r2 = 0; r2 < 4; r2++) lsum += tl[rloc][r2] * Bo[((size_t)aid * NC + col) * 4 + r2];
      out[rowg * NC + col] = x[rowg * NC + col] + acc[rr][gg] + LORA_SCALE * lsum;
    }
  }
}

// ============================================================
// Router: wave per token
// ============================================================
__global__ __launch_bounds__(256) void router_kernel(const float* __restrict__ flat,
    const float* __restrict__ Wr, const float* __restrict__ br,
    float* __restrict__ probs, float* __restrict__ top1_val, int* __restrict__ top1_idx) {
  int tid = threadIdx.x;
  int lane = tid & 63, w = tid >> 6;
  int token = blockIdx.x * 4 + w;
  const float* fr = flat + (size_t)token * NC;
  float p0 = 0.f, p1 = 0.f, p2 = 0.f, p3 = 0.f;
  for (int c = lane; c < NC; c += 64) {
    float f = fr[c];
    const float4 wr = *(const float4*)(Wr + c * 4);
    p0 += f * wr.x; p1 += f * wr.y; p2 += f * wr.z; p3 += f * wr.w;
  }
#pragma unroll
  for (int off = 32; off > 0; off >>= 1) {
    p0 += __shfl_xor(p0, off); p1 += __shfl_xor(p1, off);
    p2 += __shfl_xor(p2, off); p3 += __shfl_xor(p3, off);
  }
  if (lane == 0) {
    float l0 = p0 + br[0], l1 = p1 + br[1], l2 = p2 + br[2], l3 = p3 + br[3];
    float mx = fmaxf(fmaxf(l0, l1), fmaxf(l2, l3));
    float e0 = expf(l0 - mx), e1 = expf(l1 - mx), e2 = expf(l2 - mx), e3 = expf(l3 - mx);
    float inv = 1.f / (e0 + e1 + e2 + e3);
    float q0 = e0 * inv, q1 = e1 * inv, q2 = e2 * inv, q3 = e3 * inv;
    probs[token * 4 + 0] = q0; probs[token * 4 + 1] = q1;
    probs[token * 4 + 2] = q2; probs[token * 4 + 3] = q3;
    int best = 0; float bv = q0;
    if (q1 > bv) { bv = q1; best = 1; }
    if (q2 > bv) { bv = q2; best = 2; }
    if (q3 > bv) { bv = q3; best = 3; }
    top1_idx[token] = best;
    top1_val[token] = bv;
  }
}

// ============================================================
// Scan: deterministic rank within expert (cumsum order), slot list, aux
// single block, 256 threads x 32 tokens
// ============================================================
__global__ __launch_bounds__(256) void scan_kernel(const int* __restrict__ top1_idx,
    const float* __restrict__ probs, int* __restrict__ slot_token,
    float* __restrict__ aux_out) {
  __shared__ float psums[4];
  __shared__ int cnts[4][256];
  __shared__ int tot[4];
  int tid = threadIdx.x;
  int base = tid * 32;
  float s0 = 0.f, s1 = 0.f, s2 = 0.f, s3 = 0.f;
  int c0 = 0, c1 = 0, c2 = 0, c3 = 0;
  for (int i = 0; i < 32; i++) {
    int tk = base + i;
    s0 += probs[tk * 4 + 0]; s1 += probs[tk * 4 + 1];
    s2 += probs[tk * 4 + 2]; s3 += probs[tk * 4 + 3];
    int e = top1_idx[tk];
    if (e == 0) c0++; else if (e == 1) c1++; else if (e == 2) c2++; else c3++;
  }
  if (tid < 4) psums[tid] = 0.f;
  cnts[0][tid] = c0; cnts[1][tid] = c1; cnts[2][tid] = c2; cnts[3][tid] = c3;
  __syncthreads();
#pragma unroll
  for (int off = 32; off > 0; off >>= 1) {
    s0 += __shfl_xor(s0, off); s1 += __shfl_xor(s1, off);
    s2 += __shfl_xor(s2, off); s3 += __shfl_xor(s3, off);
  }
  if ((tid & 63) == 0) {
    atomicAdd(&psums[0], s0); atomicAdd(&psums[1], s1);
    atomicAdd(&psums[2], s2); atomicAdd(&psums[3], s3);
  }
  // per-expert exclusive scan over 256 thread-counts; wave w handles expert w
  int w = tid >> 6, lane = tid & 63;
  int v0 = cnts[w][lane * 4 + 0], v1 = cnts[w][lane * 4 + 1];
  int v2 = cnts[w][lane * 4 + 2], v3 = cnts[w][lane * 4 + 3];
  int t4 = v0 + v1 + v2 + v3;
  int incl = t4;
#pragma unroll
  for (int off = 1; off < 64; off <<= 1) {
    int n = __shfl_up(incl, off);
    if (lane >= off) incl += n;
  }
  int excl = incl - t4;
  __syncthreads();
  cnts[w][lane * 4 + 0] = excl;
  cnts[w][lane * 4 + 1] = excl + v0;
  cnts[w][lane * 4 + 2] = excl + v0 + v1;
  cnts[w][lane * 4 + 3] = excl + v0 + v1 + v2;
  if (lane == 63) tot[w] = incl;
  __syncthreads();
  int pe0 = cnts[0][tid], pe1 = cnts[1][tid], pe2 = cnts[2][tid], pe3 = cnts[3][tid];
  for (int i = 0; i < 32; i++) {
    int tk = base + i;
    int e = top1_idx[tk];
    int r;
    if (e == 0) r = pe0++;
    else if (e == 1) r = pe1++;
    else if (e == 2) r = pe2++;
    else r = pe3++;
    if (r < NCAP) slot_token[e * NCAP + r] = tk;
  }
  __syncthreads();
  if (tid == 0) {
    float aux = 0.f;
#pragma unroll
    for (int e = 0; e < 4; e++) {
      int d = tot[e] < NCAP ? tot[e] : NCAP;
      aux += (psums[e] * (1.f / NTOKENS)) * ((float)d * (1.f / NTOKENS));
    }
    aux_out[0] = aux * (float)NEXP;
  }
}

// ============================================================
// Fused expert FFN (W1+relu+W2 with LoRA), gathering dispatched tokens.
// grid (NCAP/16, NEXP); 16 slots/block; h1 chunk (512) staged in LDS.
// ============================================================
__global__ __launch_bounds__(256) void ffn_kernel(const float* __restrict__ flat,
    const int* __restrict__ aidp, const int* __restrict__ slot_token,
    const float* __restrict__ top1_val,
    const float* __restrict__ W1, const float* __restrict__ A1, const float* __restrict__ B1,
    const float* __restrict__ W2, const float* __restrict__ A2, const float* __restrict__ B2,
    float* __restrict__ out) {
  __shared__ float ft[16][385];
  __shared__ float hc[16][513];
  __shared__ float t1[16][4];
  __shared__ float t2[16][4];
  __shared__ int toks[16];
  __shared__ float gates[16];
  int aid = aidp[0];
  int e = blockIdx.y;
  int s0 = blockIdx.x * 16;
  int tid = threadIdx.x;
  if (tid < 16) {
    int tk = slot_token[e * NCAP + s0 + tid];
    toks[tid] = tk;
    gates[tid] = (tk >= 0) ? top1_val[tk] : 0.f;
  }
  __syncthreads();
  for (int i = tid; i < 16 * NC; i += 256) {
    int r = i / NC, c = i - r * NC;
    int tk = toks[r];
    ft[r][c] = (tk >= 0) ? flat[(size_t)tk * NC + c] : 0.f;
  }
  __syncthreads();
  if (tid < 64) {
    int r = tid >> 2, rr = tid & 3;
    const float* Arow = A1 + (((size_t)e * 4 + aid) * NR + rr) * NC;
    float s = 0.f;
    for (int c = 0; c < NC; c++) s += ft[r][c] * Arow[c];
    t1[r][rr] = s;
  }
  __syncthreads();
  int tx = tid & 63, ty = tid >> 6;
  float acc2[4][6];
#pragma unroll
  for (int a = 0; a < 4; a++)
#pragma unroll
    for (int gg = 0; gg < 6; gg++) acc2[a][gg] = 0.f;
  float t2part = 0.f;
  for (int ch = 0; ch < 3; ch++) {
    float acc1[4][8];
#pragma unroll
    for (int a = 0; a < 4; a++)
#pragma unroll
      for (int gg = 0; gg < 8; gg++) acc1[a][gg] = 0.f;
    for (int c = 0; c < NC; c++) {
      float hv[4];
#pragma unroll
      for (int rr = 0; rr < 4; rr++) hv[rr] = ft[ty + rr * 4][c];
      const float* wrow = W1 + ((size_t)e * NC + c) * NFF + ch * 512;
#pragma unroll
      for (int gg = 0; gg < 8; gg++) {
        float wv = wrow[gg * 64 + tx];
#pragma unroll
        for (int rr = 0; rr < 4; rr++) acc1[rr][gg] += hv[rr] * wv;
      }
    }
#pragma unroll
    for (int rr = 0; rr < 4; rr++) {
      int rloc = ty + rr * 4;
#pragma unroll
      for (int gg = 0; gg < 8; gg++) {
        int col = ch * 512 + gg * 64 + tx;
        float ls = 0.f;
#pragma unroll
        for (int r2 = 0; r2 < 4; r2++)
          ls += t1[rloc][r2] * B1[(((size_t)e * 4 + aid) * NFF + col) * 4 + r2];
        float hval = acc1[rr][gg] + LORA_SCALE * ls;
        hc[rloc][gg * 64 + tx] = fmaxf(hval, 0.f);
      }
    }
    __syncthreads();
    if (tid < 64) {
      int r = tid >> 2, rr = tid & 3;
      const float* A2row = A2 + (((size_t)e * 4 + aid) * NR + rr) * NFF + ch * 512;
      float s = 0.f;
      for (int c = 0; c < 512; c++) s += hc[r][c] * A2row[c];
      t2part += s;
    }
    for (int c = 0; c < 512; c++) {
      float hv[4];
#pragma unroll
      for (int rr = 0; rr < 4; rr++) hv[rr] = hc[ty + rr * 4][c];
      const float* wrow = W2 + ((size_t)e * NFF + ch * 512 + c) * NC;
#pragma unroll
      for (int gg = 0; gg < 6; gg++) {
        float wv = wrow[gg * 64 + tx];
#pragma unroll
        for (int rr = 0; rr < 4; rr++) acc2[rr][gg] += hv[rr] * wv;
      }
    }
    __syncthreads();
  }
  if (tid < 64) { int r = tid >> 2, rr = tid & 3; t2[r][rr] = t2part; }
  __syncthreads();
#pragma unroll
  for (int rr = 0; rr < 4; rr++) {
    int rloc = ty + rr * 4;
    int tk = toks[rloc];
    if (tk < 0) continue;
    float gate = gates[rloc];
#pragma unroll
    for (int gg = 0; gg < 6; gg++) {
      int col = gg * 64 + tx;
      float ls = 0.f;
#pragma unroll
      for (int r2 = 0; r2 < 4; r2++)
        ls += t2[rloc][r2] * B2[(((size_t)e * 4 + aid) * NC + col) * 4 + r2];
      float val = (acc2[rr][gg] + LORA_SCALE * ls) * gate;
      out[(size_t)tk * NC + col] += val;
    }
  }
}

// ============================================================
extern "C" void kernel_launch(void* const* d_in, const int* in_sizes, int n_in,
                              void* d_out, int out_size, void* d_ws, size_t ws_size,
                              hipStream_t stream) {
  const float* x   = (const float*)d_in[0];
  const int*   aid = (const int*)d_in[1];
  const float* ln1g = (const float*)d_in[2];
  const float* ln1b = (const float*)d_in[3];
  const float* ln2g = (const float*)d_in[4];
  const float* ln2b = (const float*)d_in[5];
  const float* Wq = (const float*)d_in[6];
  const float* Aq = (const float*)d_in[7];
  const float* Bq = (const float*)d_in[8];
  const float* Wk = (const float*)d_in[9];
  const float* Ak = (const float*)d_in[10];
  const float* Bk = (const float*)d_in[11];
  const float* Wv = (const float*)d_in[12];
  const float* Av = (const float*)d_in[13];
  const float* Bv = (const float*)d_in[14];
  const float* Wo = (const float*)d_in[15];
  const float* Ao = (const float*)d_in[16];
  const float* Bo = (const float*)d_in[17];
  const float* Wr = (const float*)d_in[18];
  const float* br = (const float*)d_in[19];
  const float* W1 = (const float*)d_in[20];
  const float* A1 = (const float*)d_in[21];
  const float* B1 = (const float*)d_in[22];
  const float* W2 = (const float*)d_in[23];
  const float* A2 = (const float*)d_in[24];
  const float* B2 = (const float*)d_in[25];
  float* out = (float*)d_out;
  float* ws = (float*)d_ws;

  float* h     = ws + OFF_H;
  float* q     = ws + OFF_Q;
  float* k     = ws + OFF_K;
  float* v     = ws + OFF_V;
  float* o     = ws + OFF_O;
  float* flat  = ws + OFF_FLAT;
  float* Wpk   = ws + OFF_WPK;
  float* Bpk   = ws + OFF_BPK;
  float* probs = ws + OFF_PROBS;
  float* t1v   = ws + OFF_T1V;
  int*   t1i   = (int*)(ws + OFF_T1I);
  int*   slot  = (int*)(ws + OFF_SLOT);

  pack_kernel<<<(NC * NQKV + 255) / 256, 256, 0, stream>>>(aid, Wq, Bq, Wk, Bk, Wv, Bv, Wpk, Bpk, slot);
  ln_kernel<<<NTOKENS / 4, 256, 0, stream>>>(x, ln1g, ln1b, h);
  qkv_kernel<<<NTOKENS / 16, 256, 0, stream>>>(h, aid, Wpk, Bpk, Aq, Ak, Av, q, k, v);
  rope_kernel<<<(NB * NHQ * NT * 24 + 255) / 256, 256, 0, stream>>>(q, NB * NHQ * NT * 24);
  rope_kernel<<<(NB * NHKV * NT * 24 + 255) / 256, 256, 0, stream>>>(k, NB * NHKV * NT * 24);
  attn_kernel<<<dim3(NT / 32, NB * NHQ), 256, 0, stream>>>(q, k, v, o);
  proj_kernel<<<NTOKENS / 16, 256, 0, stream>>>(o, x, aid, Wo, Ao, Bo, out);
  ln_kernel<<<NTOKENS / 4, 256, 0, stream>>>(out, ln2g, ln2b, flat);
  router_kernel<<<NTOKENS / 4, 256, 0, stream>>>(flat, Wr, br, probs, t1v, t1i);
  scan_kernel<<<1, 256, 0, stream>>>(t1i, probs, slot, out + (size_t)NTOKENS * NC);
  ffn_kernel<<<dim3(NCAP / 16, NEXP), 256, 0, stream>>>(flat, aid, slot, t1v,
      W1, A1, B1, W2, A2, B2, out);
}

// Round 3
// 1418.660 us; speedup vs baseline: 1.6522x; 1.6522x over previous
//
#include <hip/hip_runtime.h>
#include <math.h>

// ---- problem constants ----
#define NC   384
#define NHQ  8
#define NHKV 2
#define NHD  48
#define NR   4
#define NEXP 4
#define NB   4
#define NT   2048
#define NTOKENS 8192
#define NCAP 2560
#define NFF  1536
#define NQKV 576
#define LORA_SCALE 0.25f

// ---- ws layout (float offsets) ----
#define OFF_H     ((size_t)0)          // h (ln1 out), later reused as flat (ln2 out)
#define OFF_Q     ((size_t)3145728)
#define OFF_K     ((size_t)6291456)
#define OFF_V     ((size_t)7077888)
#define OFF_O     ((size_t)7864320)
#define OFF_WOEF  ((size_t)11010048)   // 147456 f32 (Wo folded)
#define OFF_W1T   ((size_t)11157504)   // 2359296 ushort = 1179648 f32 slots (W1T bf16, [E][F][C])
#define OFF_W2T   ((size_t)12337152)   // 2359296 ushort (W2T bf16, [E][C][F])
#define OFF_WPK   ((size_t)14155776)   // 221184 f32 (Wqkv folded)
#define OFF_PROBS ((size_t)14379264)
#define OFF_T1V   ((size_t)14412032)
#define OFF_T1I   ((size_t)14420224)
#define OFF_SLOT  ((size_t)14428416)

typedef short bf16x8 __attribute__((ext_vector_type(8)));
typedef float f32x4  __attribute__((ext_vector_type(4)));

__device__ __forceinline__ unsigned short f2bf(float x) {
  union { float f; unsigned u; } a; a.f = x;
  unsigned r = a.u + 0x7FFFu + ((a.u >> 16) & 1u);
  return (unsigned short)(r >> 16);
}

#define C4(v,i) ((i)==0?(v).x:((i)==1?(v).y:((i)==2?(v).z:(v).w)))

// ============================================================
// LayerNorm: one wave per row, 4 rows/block
// ============================================================
__global__ __launch_bounds__(256) void ln_kernel(const float* __restrict__ x,
    const float* __restrict__ g, const float* __restrict__ bb,
    float* __restrict__ out) {
  int row = blockIdx.x * 4 + (threadIdx.x >> 6);
  int lane = threadIdx.x & 63;
  const float* xr = x + (size_t)row * NC;
  float v0[6];
  float s = 0.f;
#pragma unroll
  for (int i = 0; i < 6; i++) { v0[i] = xr[lane + i * 64]; s += v0[i]; }
#pragma unroll
  for (int o = 32; o > 0; o >>= 1) s += __shfl_xor(s, o);
  float mean = s * (1.f / NC);
  float s2 = 0.f;
#pragma unroll
  for (int i = 0; i < 6; i++) { float d = v0[i] - mean; s2 += d * d; }
#pragma unroll
  for (int o = 32; o > 0; o >>= 1) s2 += __shfl_xor(s2, o);
  float rstd = rsqrtf(s2 * (1.f / NC) + 1e-5f);
  float* orow = out + (size_t)row * NC;
#pragma unroll
  for (int i = 0; i < 6; i++) {
    int c = lane + i * 64;
    orow[c] = (v0[i] - mean) * rstd * g[c] + bb[c];
  }
}

// ============================================================
// Pack attention weights with LoRA folded:
//   Wpk[c][col] (384x576) = [Wq|Wk|Wv] + 0.25*A^T B^T
//   Woef[c][col] (384x384) = Wo + 0.25*Ao^T Bo^T
// Also init slot_token = -1.
// ============================================================
__global__ __launch_bounds__(256) void pack_attn_kernel(const int* __restrict__ aidp,
    const float* __restrict__ Wq, const float* __restrict__ Aq, const float* __restrict__ Bq,
    const float* __restrict__ Wk, const float* __restrict__ Ak, const float* __restrict__ Bk,
    const float* __restrict__ Wv, const float* __restrict__ Av, const float* __restrict__ Bv,
    const float* __restrict__ Wo, const float* __restrict__ Ao, const float* __restrict__ Bo,
    float* __restrict__ Wpk, float* __restrict__ Woef, int* __restrict__ slot_token) {
  int aid = aidp[0];
  int idx = blockIdx.x * 256 + threadIdx.x;
  if (idx < NC * NQKV) {
    int c = idx / NQKV, col = idx % NQKV;
    float w; const float* A; const float* B; int loc;
    if (col < 384)      { w = Wq[c * 384 + col];        A = Aq; B = Bq; loc = col; }
    else if (col < 480) { w = Wk[c * 96 + (col - 384)]; A = Ak; B = Bk; loc = col - 384; }
    else                { w = Wv[c * 96 + (col - 480)]; A = Av; B = Bv; loc = col - 480; }
    float s = 0.f;
#pragma unroll
    for (int r = 0; r < 4; r++)
      s += A[((size_t)aid * 4 + r) * NC + c] * B[((size_t)(col < 384 ? aid * 384 : aid * 96) + loc) * 4 + r];
    Wpk[idx] = w + LORA_SCALE * s;
  }
  int j = idx - NC * NQKV;
  if (j >= 0 && j < NC * NC) {
    int c = j / NC, col = j % NC;
    float s = 0.f;
#pragma unroll
    for (int r = 0; r < 4; r++)
      s += Ao[((size_t)aid * 4 + r) * NC + c] * Bo[((size_t)aid * NC + col) * 4 + r];
    Woef[j] = Wo[(size_t)c * NC + col] + LORA_SCALE * s;
  }
  if (idx < NEXP * NCAP) slot_token[idx] = -1;
}

// ============================================================
// Pack W1 -> W1T bf16 [E][F][C] with LoRA folded (tile transpose via LDS)
// grid (24 f-tiles, 6 c-tiles, 4 experts), 256 threads
// ============================================================
__global__ __launch_bounds__(256) void pack_w1t_kernel(const int* __restrict__ aidp,
    const float* __restrict__ W1, const float* __restrict__ A1, const float* __restrict__ B1,
    unsigned short* __restrict__ W1T) {
  __shared__ float tile[64][65];
  int aid = aidp[0];
  int e = blockIdx.z, cb = blockIdx.y, fb = blockIdx.x;
  int tid = threadIdx.x;
  int tlo = tid & 63, thi = tid >> 6;
  size_t la = ((size_t)e * 4 + aid);
#pragma unroll
  for (int ii = 0; ii < 16; ii++) {
    int c = cb * 64 + ii * 4 + thi;
    int f = fb * 64 + tlo;
    float val = W1[((size_t)e * NC + c) * NFF + f];
    float s = 0.f;
#pragma unroll
    for (int r = 0; r < 4; r++)
      s += A1[(la * 4 + r) * NC + c] * B1[(la * NFF + f) * 4 + r];
    tile[ii * 4 + thi][tlo] = val + LORA_SCALE * s;
  }
  __syncthreads();
#pragma unroll
  for (int ii = 0; ii < 16; ii++) {
    int floc = ii * 4 + thi;
    W1T[((size_t)e * NFF + fb * 64 + floc) * NC + cb * 64 + tlo] = f2bf(tile[tlo][floc]);
  }
}

// ============================================================
// Pack W2 -> W2T bf16 [E][C][F] with LoRA folded
// grid (24 f-tiles, 6 c-tiles, 4 experts)
// ============================================================
__global__ __launch_bounds__(256) void pack_w2t_kernel(const int* __restrict__ aidp,
    const float* __restrict__ W2, const float* __restrict__ A2, const float* __restrict__ B2,
    unsigned short* __restrict__ W2T) {
  __shared__ float tile[64][65];
  int aid = aidp[0];
  int e = blockIdx.z, cb = blockIdx.y, fb = blockIdx.x;
  int tid = threadIdx.x;
  int tlo = tid & 63, thi = tid >> 6;
  size_t la = ((size_t)e * 4 + aid);
#pragma unroll
  for (int ii = 0; ii < 16; ii++) {
    int f = fb * 64 + ii * 4 + thi;
    int c = cb * 64 + tlo;
    float val = W2[((size_t)e * NFF + f) * NC + c];
    float s = 0.f;
#pragma unroll
    for (int r = 0; r < 4; r++)
      s += A2[(la * 4 + r) * NFF + f] * B2[(la * NC + c) * 4 + r];
    tile[ii * 4 + thi][tlo] = val + LORA_SCALE * s;   // tile[f_loc][c_loc]
  }
  __syncthreads();
#pragma unroll
  for (int ii = 0; ii < 16; ii++) {
    int cloc = ii * 4 + thi;
    W2T[((size_t)e * NC + cb * 64 + cloc) * NFF + fb * 64 + tlo] = f2bf(tile[tlo][cloc]);
  }
}

// ============================================================
// QKV: h(8192x384) @ Wpk(384x576) (LoRA pre-folded); scatter to q/k/v
// ============================================================
__global__ __launch_bounds__(256) void qkv_kernel(const float* __restrict__ h,
    const float* __restrict__ Wpk,
    float* __restrict__ q, float* __restrict__ k, float* __restrict__ v) {
  __shared__ float ht[16][385];
  int row0 = blockIdx.x * 16;
  int tid = threadIdx.x;
  for (int i = tid; i < 16 * NC; i += 256) ht[i / NC][i % NC] = h[(size_t)row0 * NC + i];
  __syncthreads();
  int tx = tid & 63, ty = tid >> 6;
  float acc[4][9];
#pragma unroll
  for (int a = 0; a < 4; a++)
#pragma unroll
    for (int gg = 0; gg < 9; gg++) acc[a][gg] = 0.f;
  for (int c = 0; c < NC; c++) {
    float hv[4];
#pragma unroll
    for (int rr = 0; rr < 4; rr++) hv[rr] = ht[ty + rr * 4][c];
    const float* wrow = Wpk + (size_t)c * NQKV;
#pragma unroll
    for (int gg = 0; gg < 9; gg++) {
      float w = wrow[gg * 64 + tx];
#pragma unroll
      for (int rr = 0; rr < 4; rr++) acc[rr][gg] += hv[rr] * w;
    }
  }
#pragma unroll
  for (int rr = 0; rr < 4; rr++) {
    int rowg = row0 + ty + rr * 4;
    int b = rowg >> 11;
    int t = rowg & 2047;
#pragma unroll
    for (int gg = 0; gg < 9; gg++) {
      int col = gg * 64 + tx;
      float val = acc[rr][gg];
      if (col < 384) {
        int hh = col / 48, d = col - hh * 48;
        q[(((size_t)b * NHQ + hh) * NT + t) * NHD + d] = val;
      } else if (col < 480) {
        int c2 = col - 384; int hh = c2 / 48, d = c2 - hh * 48;
        k[(((size_t)b * NHKV + hh) * NT + t) * NHD + d] = val;
      } else {
        int c2 = col - 480; int hh = c2 / 48, d = c2 - hh * 48;
        v[(((size_t)b * NHKV + hh) * NT + t) * NHD + d] = val;
      }
    }
  }
}

// ============================================================
// RoPE in place
// ============================================================
__global__ void rope_kernel(float* __restrict__ p, int total_pairs) {
  int idx = blockIdx.x * 256 + threadIdx.x;
  if (idx >= total_pairs) return;
  int j = idx % 24;
  int rowt = idx / 24;
  int t = rowt & (NT - 1);
  float* a = p + (size_t)rowt * NHD + 2 * j;
  float ex = (float)(2 * j) * (1.f / 48.f);
  float inv = powf(10000.f, -ex);
  float ang = (float)t * inv;
  float sn, cs;
  sincosf(ang, &sn, &cs);
  float e = a[0], o = a[1];
  a[0] = e * cs - o * sn;
  a[1] = e * sn + o * cs;
}

// ============================================================
// Flash attention fp32, 64 q-rows/block, 64-wide K tiles.
// 256 threads as 16(ty: 4 q-rows each) x 16(tx: 4 k-cols / 3 d-cols).
// ============================================================
__global__ __launch_bounds__(256) void attn64_kernel(const float* __restrict__ q,
    const float* __restrict__ k, const float* __restrict__ v, float* __restrict__ o) {
  int qb = blockIdx.x;            // 0..31
  int bh = blockIdx.y;            // 0..31
  int b = bh >> 3, hq = bh & 7, hk = hq >> 2;
  const float* qp = q + (((size_t)b * NHQ + hq) * NT + qb * 64) * NHD;
  const float* kp = k + (((size_t)b * NHKV + hk) * NT) * NHD;
  const float* vp = v + (((size_t)b * NHKV + hk) * NT) * NHD;
  __shared__ float Qs[48][68];    // transposed [d][q]
  __shared__ float Ks[48][68];    // transposed [d][kc]
  __shared__ float Vs[64][49];    // row-major [kc][d]
  __shared__ float Ps[64][72];    // [q][kc]
  int tid = threadIdx.x;
  int tx = tid & 15, ty = tid >> 4;
  // stage Q transposed (d-major global reads, conflict-free LDS writes)
  for (int i = tid; i < 64 * 48; i += 256) {
    int d = i >> 6, t = i & 63;
    Qs[d][t] = qp[t * 48 + d] * 0.14433756729740643f;
  }
  float m[4], l[4], acc[4][3];
#pragma unroll
  for (int i = 0; i < 4; i++) {
    m[i] = -INFINITY; l[i] = 0.f;
    acc[i][0] = acc[i][1] = acc[i][2] = 0.f;
  }
  __syncthreads();
  int ktiles = qb + 1;
  for (int kt = 0; kt < ktiles; kt++) {
    for (int i = tid; i < 64 * 48; i += 256) {
      int d = i >> 6, t = i & 63;
      Ks[d][t] = kp[(size_t)(kt * 64 + t) * 48 + d];
    }
    for (int i = tid; i < 64 * 48; i += 256) {
      Vs[i / 48][i % 48] = vp[(size_t)kt * 64 * 48 + i];
    }
    __syncthreads();
    // QK: s[4][4] register tile
    float s[4][4];
#pragma unroll
    for (int i = 0; i < 4; i++)
#pragma unroll
      for (int j = 0; j < 4; j++) s[i][j] = 0.f;
#pragma unroll 6
    for (int d = 0; d < 48; d++) {
      float4 qv = *(const float4*)&Qs[d][ty * 4];
      float4 kv = *(const float4*)&Ks[d][tx * 4];
#pragma unroll
      for (int i = 0; i < 4; i++) {
        float qc = C4(qv, i);
        s[i][0] += qc * kv.x; s[i][1] += qc * kv.y;
        s[i][2] += qc * kv.z; s[i][3] += qc * kv.w;
      }
    }
    if (kt == qb) {   // diagonal tile: causal mask (kc > qr within tile)
#pragma unroll
      for (int i = 0; i < 4; i++)
#pragma unroll
        for (int j = 0; j < 4; j++)
          if (tx * 4 + j > ty * 4 + i) s[i][j] = -INFINITY;
    }
    // online softmax per q-row (reduce across tx group: lanes xor 1,2,4,8)
#pragma unroll
    for (int i = 0; i < 4; i++) {
      float mx = fmaxf(fmaxf(s[i][0], s[i][1]), fmaxf(s[i][2], s[i][3]));
#pragma unroll
      for (int off = 1; off < 16; off <<= 1) mx = fmaxf(mx, __shfl_xor(mx, off));
      float mnew = fmaxf(m[i], mx);
      float corr = expf(m[i] - mnew);
      m[i] = mnew;
      float ps = 0.f;
#pragma unroll
      for (int j = 0; j < 4; j++) { s[i][j] = expf(s[i][j] - mnew); ps += s[i][j]; }
#pragma unroll
      for (int off = 1; off < 16; off <<= 1) ps += __shfl_xor(ps, off);
      l[i] = l[i] * corr + ps;
      acc[i][0] *= corr; acc[i][1] *= corr; acc[i][2] *= corr;
      float4 pv4; pv4.x = s[i][0]; pv4.y = s[i][1]; pv4.z = s[i][2]; pv4.w = s[i][3];
      *(float4*)&Ps[ty * 4 + i][tx * 4] = pv4;
    }
    __syncthreads();
    // PV: acc[4 q][3 d]
#pragma unroll 4
    for (int kk = 0; kk < 16; kk++) {
      float4 pr[4];
#pragma unroll
      for (int i = 0; i < 4; i++) pr[i] = *(const float4*)&Ps[ty * 4 + i][kk * 4];
#pragma unroll
      for (int j = 0; j < 4; j++) {
        int kidx = kk * 4 + j;
        float v0 = Vs[kidx][tx * 3 + 0];
        float v1 = Vs[kidx][tx * 3 + 1];
        float v2 = Vs[kidx][tx * 3 + 2];
#pragma unroll
        for (int i = 0; i < 4; i++) {
          float p = C4(pr[i], j);
          acc[i][0] += p * v0; acc[i][1] += p * v1; acc[i][2] += p * v2;
        }
      }
    }
    __syncthreads();
  }
#pragma unroll
  for (int i = 0; i < 4; i++) {
    float inv = 1.f / l[i];
    int qglob = qb * 64 + ty * 4 + i;
    float* op = o + ((size_t)b * NT + qglob) * NC + hq * 48 + tx * 3;
    op[0] = acc[i][0] * inv; op[1] = acc[i][1] * inv; op[2] = acc[i][2] * inv;
  }
}

// ============================================================
// O-projection (LoRA pre-folded) + residual -> out
// ============================================================
__global__ __launch_bounds__(256) void proj_kernel(const float* __restrict__ o,
    const float* __restrict__ x, const float* __restrict__ Woef,
    float* __restrict__ out) {
  __shared__ float ht[16][385];
  int row0 = blockIdx.x * 16;
  int tid = threadIdx.x;
  for (int i = tid; i < 16 * NC; i += 256) ht[i / NC][i % NC] = o[(size_t)row0 * NC + i];
  __syncthreads();
  int tx = tid & 63, ty = tid >> 6;
  float acc[4][6];
#pragma unroll
  for (int a = 0; a < 4; a++)
#pragma unroll
    for (int gg = 0; gg < 6; gg++) acc[a][gg] = 0.f;
  for (int c = 0; c < NC; c++) {
    float hv[4];
#pragma unroll
    for (int rr = 0; rr < 4; rr++) hv[rr] = ht[ty + rr * 4][c];
    const float* wrow = Woef + (size_t)c * NC;
#pragma unroll
    for (int gg = 0; gg < 6; gg++) {
      float w = wrow[gg * 64 + tx];
#pragma unroll
      for (int rr = 0; rr < 4; rr++) acc[rr][gg] += hv[rr] * w;
    }
  }
#pragma unroll
  for (int rr = 0; rr < 4; rr++) {
    size_t rowg = row0 + ty + rr * 4;
#pragma unroll
    for (int gg = 0; gg < 6; gg++) {
      int col = gg * 64 + tx;
      out[rowg * NC + col] = x[rowg * NC + col] + acc[rr][gg];
    }
  }
}

// ============================================================
// Router: wave per token
// ============================================================
__global__ __launch_bounds__(256) void router_kernel(const float* __restrict__ flat,
    const float* __restrict__ Wr, const float* __restrict__ br,
    float* __restrict__ probs, float* __restrict__ top1_val, int* __restrict__ top1_idx) {
  int tid = threadIdx.x;
  int lane = tid & 63, w = tid >> 6;
  int token = blockIdx.x * 4 + w;
  const float* fr = flat + (size_t)token * NC;
  float p0 = 0.f, p1 = 0.f, p2 = 0.f, p3 = 0.f;
  for (int c = lane; c < NC; c += 64) {
    float f = fr[c];
    const float4 wr = *(const float4*)(Wr + c * 4);
    p0 += f * wr.x; p1 += f * wr.y; p2 += f * wr.z; p3 += f * wr.w;
  }
#pragma unroll
  for (int off = 32; off > 0; off >>= 1) {
    p0 += __shfl_xor(p0, off); p1 += __shfl_xor(p1, off);
    p2 += __shfl_xor(p2, off); p3 += __shfl_xor(p3, off);
  }
  if (lane == 0) {
    float l0 = p0 + br[0], l1 = p1 + br[1], l2 = p2 + br[2], l3 = p3 + br[3];
    float mx = fmaxf(fmaxf(l0, l1), fmaxf(l2, l3));
    float e0 = expf(l0 - mx), e1 = expf(l1 - mx), e2 = expf(l2 - mx), e3 = expf(l3 - mx);
    float inv = 1.f / (e0 + e1 + e2 + e3);
    float q0 = e0 * inv, q1 = e1 * inv, q2 = e2 * inv, q3 = e3 * inv;
    probs[token * 4 + 0] = q0; probs[token * 4 + 1] = q1;
    probs[token * 4 + 2] = q2; probs[token * 4 + 3] = q3;
    int best = 0; float bv = q0;
    if (q1 > bv) { bv = q1; best = 1; }
    if (q2 > bv) { bv = q2; best = 2; }
    if (q3 > bv) { bv = q3; best = 3; }
    top1_idx[token] = best;
    top1_val[token] = bv;
  }
}

// ============================================================
// Scan: deterministic rank within expert (cumsum order), slot list, aux
// ============================================================
__global__ __launch_bounds__(256) void scan_kernel(const int* __restrict__ top1_idx,
    const float* __restrict__ probs, int* __restrict__ slot_token,
    float* __restrict__ aux_out) {
  __shared__ float psums[4];
  __shared__ int cnts[4][256];
  __shared__ int tot[4];
  int tid = threadIdx.x;
  int base = tid * 32;
  float s0 = 0.f, s1 = 0.f, s2 = 0.f, s3 = 0.f;
  int c0 = 0, c1 = 0, c2 = 0, c3 = 0;
  for (int i = 0; i < 32; i++) {
    int tk = base + i;
    s0 += probs[tk * 4 + 0]; s1 += probs[tk * 4 + 1];
    s2 += probs[tk * 4 + 2]; s3 += probs[tk * 4 + 3];
    int e = top1_idx[tk];
    if (e == 0) c0++; else if (e == 1) c1++; else if (e == 2) c2++; else c3++;
  }
  if (tid < 4) psums[tid] = 0.f;
  cnts[0][tid] = c0; cnts[1][tid] = c1; cnts[2][tid] = c2; cnts[3][tid] = c3;
  __syncthreads();
#pragma unroll
  for (int off = 32; off > 0; off >>= 1) {
    s0 += __shfl_xor(s0, off); s1 += __shfl_xor(s1, off);
    s2 += __shfl_xor(s2, off); s3 += __shfl_xor(s3, off);
  }
  if ((tid & 63) == 0) {
    atomicAdd(&psums[0], s0); atomicAdd(&psums[1], s1);
    atomicAdd(&psums[2], s2); atomicAdd(&psums[3], s3);
  }
  int w = tid >> 6, lane = tid & 63;
  int v0 = cnts[w][lane * 4 + 0], v1 = cnts[w][lane * 4 + 1];
  int v2 = cnts[w][lane * 4 + 2], v3 = cnts[w][lane * 4 + 3];
  int t4 = v0 + v1 + v2 + v3;
  int incl = t4;
#pragma unroll
  for (int off = 1; off < 64; off <<= 1) {
    int n = __shfl_up(incl, off);
    if (lane >= off) incl += n;
  }
  int excl = incl - t4;
  __syncthreads();
  cnts[w][lane * 4 + 0] = excl;
  cnts[w][lane * 4 + 1] = excl + v0;
  cnts[w][lane * 4 + 2] = excl + v0 + v1;
  cnts[w][lane * 4 + 3] = excl + v0 + v1 + v2;
  if (lane == 63) tot[w] = incl;
  __syncthreads();
  int pe0 = cnts[0][tid], pe1 = cnts[1][tid], pe2 = cnts[2][tid], pe3 = cnts[3][tid];
  for (int i = 0; i < 32; i++) {
    int tk = base + i;
    int e = top1_idx[tk];
    int r;
    if (e == 0) r = pe0++;
    else if (e == 1) r = pe1++;
    else if (e == 2) r = pe2++;
    else r = pe3++;
    if (r < NCAP) slot_token[e * NCAP + r] = tk;
  }
  __syncthreads();
  if (tid == 0) {
    float aux = 0.f;
#pragma unroll
    for (int e = 0; e < 4; e++) {
      int d = tot[e] < NCAP ? tot[e] : NCAP;
      aux += (psums[e] * (1.f / NTOKENS)) * ((float)d * (1.f / NTOKENS));
    }
    aux_out[0] = aux * (float)NEXP;
  }
}

// ============================================================
// Fused expert FFN: bf16 MFMA, LoRA pre-folded into W1T/W2T.
// grid (NCAP/32, NEXP); 32 slots/block; 256 threads = 4 waves.
// Wave w: GEMM1 cols w*128..+128 (of 512-chunk), GEMM2 cols w*96..+96.
// ============================================================
__global__ __launch_bounds__(256) void ffn_mfma_kernel(const float* __restrict__ flat,
    const int* __restrict__ slot_token, const float* __restrict__ top1_val,
    const unsigned short* __restrict__ W1T, const unsigned short* __restrict__ W2T,
    float* __restrict__ out) {
  __shared__ unsigned short ft[32][384];
  __shared__ unsigned short hc[32][512];
  __shared__ int toks[32];
  __shared__ float gates[32];
  int e = blockIdx.y;
  int s0 = blockIdx.x * 32;
  int tid = threadIdx.x;
  int w = tid >> 6, lane = tid & 63;
  int row_a = lane & 15;    // A-row / B-col / D-col index
  int kgrp = lane >> 4;     // k-chunk, D-row group
  if (tid < 32) {
    int tk = slot_token[e * NCAP + s0 + tid];
    toks[tid] = tk;
    gates[tid] = (tk >= 0) ? top1_val[tk] : 0.f;
  }
  __syncthreads();
  if (toks[0] < 0) return;   // slots fill in order: empty first slot => empty block
  for (int i = tid; i < 32 * 384; i += 256) {
    int r = i >> 8 ; // i / 384? no — compute properly below
  }
  // stage ft (bf16): proper loop
  for (int i = tid; i < 32 * 384; i += 256) {
    int r = i / 384, c = i - r * 384;
    int tk = toks[r];
    float xv = (tk >= 0) ? flat[(size_t)tk * NC + c] : 0.f;
    ft[r][c] = f2bf(xv);
  }
  __syncthreads();
  f32x4 acc2[2][6];
#pragma unroll
  for (int mt = 0; mt < 2; mt++)
#pragma unroll
    for (int nt = 0; nt < 6; nt++) acc2[mt][nt] = (f32x4){0.f, 0.f, 0.f, 0.f};

  for (int ch = 0; ch < 3; ch++) {
    // ---- GEMM1: ft(32x384) @ W1T-chunk -> hc(32x512) relu bf16 ----
#pragma unroll
    for (int mt = 0; mt < 2; mt++) {
      bf16x8 a[12];
#pragma unroll
      for (int kk = 0; kk < 12; kk++)
        a[kk] = *(const bf16x8*)&ft[mt * 16 + row_a][kk * 32 + kgrp * 8];
#pragma unroll
      for (int nt = 0; nt < 8; nt++) {
        int ncol = ch * 512 + w * 128 + nt * 16 + row_a;
        const unsigned short* bp = W1T + ((size_t)e * NFF + ncol) * NC;
        f32x4 c = (f32x4){0.f, 0.f, 0.f, 0.f};
#pragma unroll
        for (int kk = 0; kk < 12; kk++) {
          bf16x8 bf = *(const bf16x8*)(bp + kk * 32 + kgrp * 8);
          c = __builtin_amdgcn_mfma_f32_16x16x32_bf16(a[kk], bf, c, 0, 0, 0);
        }
        int hcol = w * 128 + nt * 16 + row_a;
#pragma unroll
        for (int r = 0; r < 4; r++) {
          hc[mt * 16 + kgrp * 4 + r][hcol] = f2bf(fmaxf(c[r], 0.f));
        }
      }
    }
    __syncthreads();
    // ---- GEMM2: hc(32x512) @ W2T-chunk -> acc2 (32x384) ----
#pragma unroll
    for (int mt = 0; mt < 2; mt++) {
      bf16x8 a2[16];
#pragma unroll
      for (int kk = 0; kk < 16; kk++)
        a2[kk] = *(const bf16x8*)&hc[mt * 16 + row_a][kk * 32 + kgrp * 8];
#pragma unroll
      for (int nt = 0; nt < 6; nt++) {
        int ncol = w * 96 + nt * 16 + row_a;
        const unsigned short* bp = W2T + ((size_t)e * NC + ncol) * NFF + ch * 512;
        f32x4 c = acc2[mt][nt];
#pragma unroll
        for (int kk = 0; kk < 16; kk++) {
          bf16x8 bf = *(const bf16x8*)(bp + kk * 32 + kgrp * 8);
          c = __builtin_amdgcn_mfma_f32_16x16x32_bf16(a2[kk], bf, c, 0, 0, 0);
        }
        acc2[mt][nt] = c;
      }
    }
    __syncthreads();
  }
  // epilogue: out[tk] += acc2 * gate
#pragma unroll
  for (int mt = 0; mt < 2; mt++) {
#pragma unroll
    for (int r = 0; r < 4; r++) {
      int srow = mt * 16 + kgrp * 4 + r;
      int tk = toks[srow];
      if (tk < 0) continue;
      float g = gates[srow];
#pragma unroll
      for (int nt = 0; nt < 6; nt++) {
        int col = w * 96 + nt * 16 + row_a;
        out[(size_t)tk * NC + col] += acc2[mt][nt][r] * g;
      }
    }
  }
}

// ============================================================
extern "C" void kernel_launch(void* const* d_in, const int* in_sizes, int n_in,
                              void* d_out, int out_size, void* d_ws, size_t ws_size,
                              hipStream_t stream) {
  const float* x   = (const float*)d_in[0];
  const int*   aid = (const int*)d_in[1];
  const float* ln1g = (const float*)d_in[2];
  const float* ln1b = (const float*)d_in[3];
  const float* ln2g = (const float*)d_in[4];
  const float* ln2b = (const float*)d_in[5];
  const float* Wq = (const float*)d_in[6];
  const float* Aq = (const float*)d_in[7];
  const float* Bq = (const float*)d_in[8];
  const float* Wk = (const float*)d_in[9];
  const float* Ak = (const float*)d_in[10];
  const float* Bk = (const float*)d_in[11];
  const float* Wv = (const float*)d_in[12];
  const float* Av = (const float*)d_in[13];
  const float* Bv = (const float*)d_in[14];
  const float* Wo = (const float*)d_in[15];
  const float* Ao = (const float*)d_in[16];
  const float* Bo = (const float*)d_in[17];
  const float* Wr = (const float*)d_in[18];
  const float* br = (const float*)d_in[19];
  const float* W1 = (const float*)d_in[20];
  const float* A1 = (const float*)d_in[21];
  const float* B1 = (const float*)d_in[22];
  const float* W2 = (const float*)d_in[23];
  const float* A2 = (const float*)d_in[24];
  const float* B2 = (const float*)d_in[25];
  float* out = (float*)d_out;
  float* ws = (float*)d_ws;

  float* h     = ws + OFF_H;
  float* flat  = ws + OFF_H;   // reuses h after it is dead
  float* q     = ws + OFF_Q;
  float* k     = ws + OFF_K;
  float* v     = ws + OFF_V;
  float* o     = ws + OFF_O;
  float* Woef  = ws + OFF_WOEF;
  unsigned short* W1T = (unsigned short*)(ws + OFF_W1T);
  unsigned short* W2T = (unsigned short*)(ws + OFF_W2T);
  float* Wpk   = ws + OFF_WPK;
  float* probs = ws + OFF_PROBS;
  float* t1v   = ws + OFF_T1V;
  int*   t1i   = (int*)(ws + OFF_T1I);
  int*   slot  = (int*)(ws + OFF_SLOT);

  pack_attn_kernel<<<1440, 256, 0, stream>>>(aid, Wq, Aq, Bq, Wk, Ak, Bk, Wv, Av, Bv,
                                             Wo, Ao, Bo, Wpk, Woef, slot);
  pack_w1t_kernel<<<dim3(24, 6, 4), 256, 0, stream>>>(aid, W1, A1, B1, W1T);
  pack_w2t_kernel<<<dim3(24, 6, 4), 256, 0, stream>>>(aid, W2, A2, B2, W2T);
  ln_kernel<<<NTOKENS / 4, 256, 0, stream>>>(x, ln1g, ln1b, h);
  qkv_kernel<<<NTOKENS / 16, 256, 0, stream>>>(h, Wpk, q, k, v);
  rope_kernel<<<(NB * NHQ * NT * 24 + 255) / 256, 256, 0, stream>>>(q, NB * NHQ * NT * 24);
  rope_kernel<<<(NB * NHKV * NT * 24 + 255) / 256, 256, 0, stream>>>(k, NB * NHKV * NT * 24);
  attn64_kernel<<<dim3(NT / 64, NB * NHQ), 256, 0, stream>>>(q, k, v, o);
  proj_kernel<<<NTOKENS / 16, 256, 0, stream>>>(o, x, Woef, out);
  ln_kernel<<<NTOKENS / 4, 256, 0, stream>>>(out, ln2g, ln2b, flat);
  router_kernel<<<NTOKENS / 4, 256, 0, stream>>>(flat, Wr, br, probs, t1v, t1i);
  scan_kernel<<<1, 256, 0, stream>>>(t1i, probs, slot, out + (size_t)NTOKENS * NC);
  ffn_mfma_kernel<<<dim3(NCAP / 32, NEXP), 256, 0, stream>>>(flat, slot, t1v, W1T, W2T, out);
}

// Round 4
// 946.787 us; speedup vs baseline: 2.4757x; 1.4984x over previous
//
#include <hip/hip_runtime.h>
#include <math.h>

// ---- problem constants ----
#define NC   384
#define NHQ  8
#define NHKV 2
#define NHD  48
#define NR   4
#define NEXP 4
#define NB   4
#define NT   2048
#define NTOKENS 8192
#define NCAP 2560
#define NFF  1536
#define NQKV 576
#define LORA_SCALE 0.25f
#define L2E 1.4426950408889634f

// ---- ws layout (float offsets) ----
#define OFF_H     ((size_t)0)          // h (ln1 out) -> then qhi/qlo bf16 -> then flat (ln2 out)
#define OFF_Q     ((size_t)3145728)    // q fp32 -> then khi/klo/vthi/vtlo bf16
#define OFF_K     ((size_t)6291456)
#define OFF_V     ((size_t)7077888)
#define OFF_O     ((size_t)7864320)
#define OFF_WOEF  ((size_t)11010048)
#define OFF_W1T   ((size_t)11157504)
#define OFF_W2T   ((size_t)12337152)
#define OFF_WPK   ((size_t)14155776)
#define OFF_PROBS ((size_t)14379264)
#define OFF_T1V   ((size_t)14412032)
#define OFF_T1I   ((size_t)14420224)
#define OFF_SLOT  ((size_t)14428416)

typedef short bf16x8 __attribute__((ext_vector_type(8)));
typedef float f32x4  __attribute__((ext_vector_type(4)));

__device__ __forceinline__ unsigned short f2bf(float x) {
  union { float f; unsigned u; } a; a.f = x;
  unsigned r = a.u + 0x7FFFu + ((a.u >> 16) & 1u);
  return (unsigned short)(r >> 16);
}
__device__ __forceinline__ float bf2f(unsigned short h) {
  union { unsigned u; float f; } a; a.u = ((unsigned)h) << 16; return a.f;
}

#define MFMA16(a, b, c) __builtin_amdgcn_mfma_f32_16x16x32_bf16((a), (b), (c), 0, 0, 0)

// ============================================================
// LayerNorm: one wave per row, 4 rows/block
// ============================================================
__global__ __launch_bounds__(256) void ln_kernel(const float* __restrict__ x,
    const float* __restrict__ g, const float* __restrict__ bb,
    float* __restrict__ out) {
  int row = blockIdx.x * 4 + (threadIdx.x >> 6);
  int lane = threadIdx.x & 63;
  const float* xr = x + (size_t)row * NC;
  float v0[6];
  float s = 0.f;
#pragma unroll
  for (int i = 0; i < 6; i++) { v0[i] = xr[lane + i * 64]; s += v0[i]; }
#pragma unroll
  for (int o = 32; o > 0; o >>= 1) s += __shfl_xor(s, o);
  float mean = s * (1.f / NC);
  float s2 = 0.f;
#pragma unroll
  for (int i = 0; i < 6; i++) { float d = v0[i] - mean; s2 += d * d; }
#pragma unroll
  for (int o = 32; o > 0; o >>= 1) s2 += __shfl_xor(s2, o);
  float rstd = rsqrtf(s2 * (1.f / NC) + 1e-5f);
  float* orow = out + (size_t)row * NC;
#pragma unroll
  for (int i = 0; i < 6; i++) {
    int c = lane + i * 64;
    orow[c] = (v0[i] - mean) * rstd * g[c] + bb[c];
  }
}

// ============================================================
// Pack attention weights with LoRA folded; init slot_token
// ============================================================
__global__ __launch_bounds__(256) void pack_attn_kernel(const int* __restrict__ aidp,
    const float* __restrict__ Wq, const float* __restrict__ Aq, const float* __restrict__ Bq,
    const float* __restrict__ Wk, const float* __restrict__ Ak, const float* __restrict__ Bk,
    const float* __restrict__ Wv, const float* __restrict__ Av, const float* __restrict__ Bv,
    const float* __restrict__ Wo, const float* __restrict__ Ao, const float* __restrict__ Bo,
    float* __restrict__ Wpk, float* __restrict__ Woef, int* __restrict__ slot_token) {
  int aid = aidp[0];
  int idx = blockIdx.x * 256 + threadIdx.x;
  if (idx < NC * NQKV) {
    int c = idx / NQKV, col = idx % NQKV;
    float w; const float* A; const float* B; int loc;
    if (col < 384)      { w = Wq[c * 384 + col];        A = Aq; B = Bq; loc = col; }
    else if (col < 480) { w = Wk[c * 96 + (col - 384)]; A = Ak; B = Bk; loc = col - 384; }
    else                { w = Wv[c * 96 + (col - 480)]; A = Av; B = Bv; loc = col - 480; }
    float s = 0.f;
#pragma unroll
    for (int r = 0; r < 4; r++)
      s += A[((size_t)aid * 4 + r) * NC + c] * B[((size_t)(col < 384 ? aid * 384 : aid * 96) + loc) * 4 + r];
    Wpk[idx] = w + LORA_SCALE * s;
  }
  int j = idx - NC * NQKV;
  if (j >= 0 && j < NC * NC) {
    int c = j / NC, col = j % NC;
    float s = 0.f;
#pragma unroll
    for (int r = 0; r < 4; r++)
      s += Ao[((size_t)aid * 4 + r) * NC + c] * Bo[((size_t)aid * NC + col) * 4 + r];
    Woef[j] = Wo[(size_t)c * NC + col] + LORA_SCALE * s;
  }
  if (idx < NEXP * NCAP) slot_token[idx] = -1;
}

// ============================================================
// Pack W1 -> W1T bf16 [E][F][C] with LoRA folded
// ============================================================
__global__ __launch_bounds__(256) void pack_w1t_kernel(const int* __restrict__ aidp,
    const float* __restrict__ W1, const float* __restrict__ A1, const float* __restrict__ B1,
    unsigned short* __restrict__ W1T) {
  __shared__ float tile[64][65];
  int aid = aidp[0];
  int e = blockIdx.z, cb = blockIdx.y, fb = blockIdx.x;
  int tid = threadIdx.x;
  int tlo = tid & 63, thi = tid >> 6;
  size_t la = ((size_t)e * 4 + aid);
#pragma unroll
  for (int ii = 0; ii < 16; ii++) {
    int c = cb * 64 + ii * 4 + thi;
    int f = fb * 64 + tlo;
    float val = W1[((size_t)e * NC + c) * NFF + f];
    float s = 0.f;
#pragma unroll
    for (int r = 0; r < 4; r++)
      s += A1[(la * 4 + r) * NC + c] * B1[(la * NFF + f) * 4 + r];
    tile[ii * 4 + thi][tlo] = val + LORA_SCALE * s;
  }
  __syncthreads();
#pragma unroll
  for (int ii = 0; ii < 16; ii++) {
    int floc = ii * 4 + thi;
    W1T[((size_t)e * NFF + fb * 64 + floc) * NC + cb * 64 + tlo] = f2bf(tile[tlo][floc]);
  }
}

// ============================================================
// Pack W2 -> W2T bf16 [E][C][F] with LoRA folded
// ============================================================
__global__ __launch_bounds__(256) void pack_w2t_kernel(const int* __restrict__ aidp,
    const float* __restrict__ W2, const float* __restrict__ A2, const float* __restrict__ B2,
    unsigned short* __restrict__ W2T) {
  __shared__ float tile[64][65];
  int aid = aidp[0];
  int e = blockIdx.z, cb = blockIdx.y, fb = blockIdx.x;
  int tid = threadIdx.x;
  int tlo = tid & 63, thi = tid >> 6;
  size_t la = ((size_t)e * 4 + aid);
#pragma unroll
  for (int ii = 0; ii < 16; ii++) {
    int f = fb * 64 + ii * 4 + thi;
    int c = cb * 64 + tlo;
    float val = W2[((size_t)e * NFF + f) * NC + c];
    float s = 0.f;
#pragma unroll
    for (int r = 0; r < 4; r++)
      s += A2[(la * 4 + r) * NFF + f] * B2[(la * NC + c) * 4 + r];
    tile[ii * 4 + thi][tlo] = val + LORA_SCALE * s;
  }
  __syncthreads();
#pragma unroll
  for (int ii = 0; ii < 16; ii++) {
    int cloc = ii * 4 + thi;
    W2T[((size_t)e * NC + cb * 64 + cloc) * NFF + fb * 64 + tlo] = f2bf(tile[tlo][cloc]);
  }
}

// ============================================================
// QKV: h(8192x384) @ Wpk(384x576); scatter to q/k/v fp32 [b][h][t][48]
// ============================================================
__global__ __launch_bounds__(256) void qkv_kernel(const float* __restrict__ h,
    const float* __restrict__ Wpk,
    float* __restrict__ q, float* __restrict__ k, float* __restrict__ v) {
  __shared__ float ht[16][385];
  int row0 = blockIdx.x * 16;
  int tid = threadIdx.x;
  for (int i = tid; i < 16 * NC; i += 256) ht[i / NC][i % NC] = h[(size_t)row0 * NC + i];
  __syncthreads();
  int tx = tid & 63, ty = tid >> 6;
  float acc[4][9];
#pragma unroll
  for (int a = 0; a < 4; a++)
#pragma unroll
    for (int gg = 0; gg < 9; gg++) acc[a][gg] = 0.f;
  for (int c = 0; c < NC; c++) {
    float hv[4];
#pragma unroll
    for (int rr = 0; rr < 4; rr++) hv[rr] = ht[ty + rr * 4][c];
    const float* wrow = Wpk + (size_t)c * NQKV;
#pragma unroll
    for (int gg = 0; gg < 9; gg++) {
      float w = wrow[gg * 64 + tx];
#pragma unroll
      for (int rr = 0; rr < 4; rr++) acc[rr][gg] += hv[rr] * w;
    }
  }
#pragma unroll
  for (int rr = 0; rr < 4; rr++) {
    int rowg = row0 + ty + rr * 4;
    int b = rowg >> 11;
    int t = rowg & 2047;
#pragma unroll
    for (int gg = 0; gg < 9; gg++) {
      int col = gg * 64 + tx;
      float val = acc[rr][gg];
      if (col < 384) {
        int hh = col / 48, d = col - hh * 48;
        q[(((size_t)b * NHQ + hh) * NT + t) * NHD + d] = val;
      } else if (col < 480) {
        int c2 = col - 384; int hh = c2 / 48, d = c2 - hh * 48;
        k[(((size_t)b * NHKV + hh) * NT + t) * NHD + d] = val;
      } else {
        int c2 = col - 480; int hh = c2 / 48, d = c2 - hh * 48;
        v[(((size_t)b * NHKV + hh) * NT + t) * NHD + d] = val;
      }
    }
  }
}

// ============================================================
// prep_q: rope + scale + hi/lo bf16 split. out [bh][t][48]
// ============================================================
__global__ __launch_bounds__(256) void prep_q_kernel(const float* __restrict__ q,
    unsigned short* __restrict__ qhi, unsigned short* __restrict__ qlo) {
  int row = blockIdx.x * 256 + threadIdx.x;   // bh*2048 + t
  int t = row & 2047;
  const float* src = q + (size_t)row * 48;
  float xr[48];
#pragma unroll
  for (int i = 0; i < 12; i++) *(float4*)&xr[i * 4] = *(const float4*)&src[i * 4];
#pragma unroll
  for (int j = 0; j < 24; j++) {
    float inv = powf(10000.f, -(float)(2 * j) * (1.f / 48.f));
    float sn, cs; sincosf((float)t * inv, &sn, &cs);
    float e = xr[2 * j], od = xr[2 * j + 1];
    xr[2 * j]     = (e * cs - od * sn) * 0.14433756729740643f;
    xr[2 * j + 1] = (e * sn + od * cs) * 0.14433756729740643f;
  }
  alignas(16) unsigned int bh[24], bl[24];
#pragma unroll
  for (int i = 0; i < 24; i++) {
    unsigned short h0 = f2bf(xr[2 * i]);
    unsigned short h1 = f2bf(xr[2 * i + 1]);
    unsigned short l0 = f2bf(xr[2 * i] - bf2f(h0));
    unsigned short l1 = f2bf(xr[2 * i + 1] - bf2f(h1));
    bh[i] = (unsigned)h0 | ((unsigned)h1 << 16);
    bl[i] = (unsigned)l0 | ((unsigned)l1 << 16);
  }
  unsigned short* oh = qhi + (size_t)row * 48;
  unsigned short* ol = qlo + (size_t)row * 48;
#pragma unroll
  for (int i = 0; i < 6; i++) {
    *(uint4*)(oh + i * 8) = *(uint4*)&bh[i * 4];
    *(uint4*)(ol + i * 8) = *(uint4*)&bl[i * 4];
  }
}

// ============================================================
// prep_k: rope + hi/lo split; out [bhk][t][64] padded + XOR-swizzled
// (slot-group j2 holds data-group j2 ^ (t&7); groups 6,7 = zero pad)
// ============================================================
__global__ __launch_bounds__(256) void prep_k_kernel(const float* __restrict__ k,
    unsigned short* __restrict__ khi, unsigned short* __restrict__ klo) {
  int row = blockIdx.x * 256 + threadIdx.x;   // bhk*2048 + t
  int t = row & 2047;
  const float* src = k + (size_t)row * 48;
  float xr[48];
#pragma unroll
  for (int i = 0; i < 12; i++) *(float4*)&xr[i * 4] = *(const float4*)&src[i * 4];
#pragma unroll
  for (int j = 0; j < 24; j++) {
    float inv = powf(10000.f, -(float)(2 * j) * (1.f / 48.f));
    float sn, cs; sincosf((float)t * inv, &sn, &cs);
    float e = xr[2 * j], od = xr[2 * j + 1];
    xr[2 * j]     = e * cs - od * sn;
    xr[2 * j + 1] = e * sn + od * cs;
  }
  int sw = t & 7;
  alignas(16) unsigned int oh[32], ol[32];
#pragma unroll
  for (int j2 = 0; j2 < 8; j2++) {
    int jd = j2 ^ sw;
#pragma unroll
    for (int e2 = 0; e2 < 4; e2++) {
      unsigned short h0 = 0, h1 = 0, l0 = 0, l1 = 0;
      if (jd < 6) {
        int d = jd * 8 + e2 * 2;
        h0 = f2bf(xr[d]);     l0 = f2bf(xr[d] - bf2f(h0));
        h1 = f2bf(xr[d + 1]); l1 = f2bf(xr[d + 1] - bf2f(h1));
      }
      oh[j2 * 4 + e2] = (unsigned)h0 | ((unsigned)h1 << 16);
      ol[j2 * 4 + e2] = (unsigned)l0 | ((unsigned)l1 << 16);
    }
  }
  unsigned short* po = khi + (size_t)row * 64;
  unsigned short* pl = klo + (size_t)row * 64;
#pragma unroll
  for (int i = 0; i < 8; i++) {
    *(uint4*)(po + i * 8) = *(uint4*)&oh[i * 4];
    *(uint4*)(pl + i * 8) = *(uint4*)&ol[i * 4];
  }
}

// ============================================================
// prep_v: transpose + hi/lo split; out [bhk][d][2048], swizzled within 64-t tiles
// ============================================================
__global__ __launch_bounds__(256) void prep_v_kernel(const float* __restrict__ v,
    unsigned short* __restrict__ vthi, unsigned short* __restrict__ vtlo) {
  __shared__ float vld[64][49];
  int tt = blockIdx.x, bhk = blockIdx.y;
  int tid = threadIdx.x;
  for (int i = tid; i < 64 * 48; i += 256) {
    int r = i / 48, c = i - r * 48;
    vld[r][c] = v[((size_t)bhk * 2048 + tt * 64 + r) * 48 + c];
  }
  __syncthreads();
  for (int i = tid; i < 48 * 64; i += 256) {
    int d = i >> 6, tl = i & 63;
    float val = vld[tl ^ ((d & 7) << 3)][d];
    unsigned short h = f2bf(val);
    unsigned short lo = f2bf(val - bf2f(h));
    size_t idx = ((size_t)bhk * 48 + d) * 2048 + tt * 64 + tl;
    vthi[idx] = h; vtlo[idx] = lo;
  }
}

// ============================================================
// Flash attention, split-bf16 MFMA. 2 waves x 32q per block, K-tile 64.
// s^T = K*Q^T (lane owns one q-row), o^T = V^T*P^T.
// ============================================================
__global__ __launch_bounds__(128) void attn_mfma_kernel(
    const unsigned short* __restrict__ qhi, const unsigned short* __restrict__ qlo,
    const unsigned short* __restrict__ khi, const unsigned short* __restrict__ klo,
    const unsigned short* __restrict__ vthi, const unsigned short* __restrict__ vtlo,
    float* __restrict__ o) {
  __shared__ unsigned short Kh[4096], Kl[4096], Vh[3072], Vl[3072];
  __shared__ unsigned short Pt[2][4608];   // per-wave [32 q][144]: hi cols 0-63, lo 64-127
  const int qb = 31 - (int)blockIdx.x;     // descending for load balance
  const int bh = blockIdx.y;
  const int b = bh >> 3, hq = bh & 7, hk = hq >> 2;
  const int bhk = b * 2 + hk;
  const int tid = threadIdx.x;
  const int w = tid >> 6, lane = tid & 63;
  const int lq = lane & 15, g = lane >> 4;

  const bf16x8 zf = {0, 0, 0, 0, 0, 0, 0, 0};
  bf16x8 qfh[2][2], qfl[2][2];
  const int qbase = qb * 64 + w * 32;
#pragma unroll
  for (int qs = 0; qs < 2; qs++) {
    size_t qoff = ((size_t)bh * 2048 + qbase + qs * 16 + lq) * 48;
    qfh[qs][0] = *(const bf16x8*)(qhi + qoff + g * 8);
    qfl[qs][0] = *(const bf16x8*)(qlo + qoff + g * 8);
    if (g < 2) {
      qfh[qs][1] = *(const bf16x8*)(qhi + qoff + 32 + g * 8);
      qfl[qs][1] = *(const bf16x8*)(qlo + qoff + 32 + g * 8);
    } else { qfh[qs][1] = zf; qfl[qs][1] = zf; }
  }

  f32x4 acc[2][3];
#pragma unroll
  for (int qs = 0; qs < 2; qs++)
#pragma unroll
    for (int dt = 0; dt < 3; dt++) acc[qs][dt] = (f32x4){0.f, 0.f, 0.f, 0.f};
  float m[2] = {-1e30f, -1e30f}, l[2] = {0.f, 0.f};

  const unsigned short* kh_g = khi + (size_t)bhk * 2048 * 64;
  const unsigned short* kl_g = klo + (size_t)bhk * 2048 * 64;
  const uint4* vh4 = (const uint4*)vthi;
  const uint4* vl4 = (const uint4*)vtlo;
  const int row8 = lane >> 3, col8 = lane & 7;

  uint4 rg[16];
#define ISSUE_LOADS(KT_) do {                                                    \
    if (w == 0) {                                                                \
      const uint4* sh_ = (const uint4*)(kh_g + (size_t)(KT_) * 4096);            \
      const uint4* sl_ = (const uint4*)(kl_g + (size_t)(KT_) * 4096);            \
      _Pragma("unroll") for (int cc = 0; cc < 8; cc++) rg[cc] = sh_[cc * 64 + lane]; \
      _Pragma("unroll") for (int cc = 0; cc < 8; cc++) rg[8 + cc] = sl_[cc * 64 + lane]; \
    } else {                                                                     \
      _Pragma("unroll") for (int cc = 0; cc < 6; cc++) {                         \
        size_t idx_ = ((size_t)bhk * 48 + cc * 8 + row8) * 256 + (KT_) * 8 + col8; \
        rg[cc] = vh4[idx_]; rg[6 + cc] = vl4[idx_];                              \
      }                                                                          \
    }                                                                            \
  } while (0)

  ISSUE_LOADS(0);
  for (int kt = 0; kt <= qb; kt++) {
    __syncthreads();   // all waves done reading previous tile
    if (w == 0) {
#pragma unroll
      for (int cc = 0; cc < 8; cc++) *(uint4*)&Kh[cc * 512 + lane * 8] = rg[cc];
#pragma unroll
      for (int cc = 0; cc < 8; cc++) *(uint4*)&Kl[cc * 512 + lane * 8] = rg[8 + cc];
    } else {
#pragma unroll
      for (int cc = 0; cc < 6; cc++) *(uint4*)&Vh[cc * 512 + lane * 8] = rg[cc];
#pragma unroll
      for (int cc = 0; cc < 6; cc++) *(uint4*)&Vl[cc * 512 + lane * 8] = rg[6 + cc];
    }
    __syncthreads();
    if (kt < qb) ISSUE_LOADS(kt + 1);   // async prefetch, consumed next iter

    // ---- QK: s^T tiles ----
    f32x4 s[2][4];
#pragma unroll
    for (int qs = 0; qs < 2; qs++)
#pragma unroll
      for (int ct = 0; ct < 4; ct++) s[qs][ct] = (f32x4){0.f, 0.f, 0.f, 0.f};
#pragma unroll
    for (int c = 0; c < 2; c++) {
      const int grp = (((c << 2) + g) ^ (lq & 7)) << 3;
#pragma unroll
      for (int ct = 0; ct < 4; ct++) {
        const int ro = (ct * 16 + lq) * 64 + grp;
        bf16x8 kfh = *(const bf16x8*)&Kh[ro];
        bf16x8 kfl = *(const bf16x8*)&Kl[ro];
#pragma unroll
        for (int qs = 0; qs < 2; qs++) {
          s[qs][ct] = MFMA16(kfh, qfh[qs][c], s[qs][ct]);
          s[qs][ct] = MFMA16(kfl, qfh[qs][c], s[qs][ct]);
          s[qs][ct] = MFMA16(kfh, qfl[qs][c], s[qs][ct]);
        }
      }
    }

    // ---- mask + online softmax (per-lane q-row) ----
    const int kb4 = kt * 64 + g * 4;
#pragma unroll
    for (int qs = 0; qs < 2; qs++) {
      const int qg = qb * 64 + w * 32 + qs * 16 + lq;
#pragma unroll
      for (int ct = 0; ct < 4; ct++) {
        const int k0 = kb4 + ct * 16;
#pragma unroll
        for (int r = 0; r < 4; r++)
          if (k0 + r > qg) s[qs][ct][r] = -1e30f;
      }
      float mx = s[qs][0][0];
#pragma unroll
      for (int ct = 0; ct < 4; ct++)
#pragma unroll
        for (int r = 0; r < 4; r++) mx = fmaxf(mx, s[qs][ct][r]);
      mx = fmaxf(mx, __shfl_xor(mx, 16));
      mx = fmaxf(mx, __shfl_xor(mx, 32));
      const float mnew = fmaxf(m[qs], mx);
      const float corr = exp2f((m[qs] - mnew) * L2E);
      m[qs] = mnew;
      float ps = 0.f;
      unsigned short* prow = &Pt[w][(qs * 16 + lq) * 144];
#pragma unroll
      for (int ct = 0; ct < 4; ct++) {
        float p0 = exp2f((s[qs][ct][0] - mnew) * L2E);
        float p1 = exp2f((s[qs][ct][1] - mnew) * L2E);
        float p2 = exp2f((s[qs][ct][2] - mnew) * L2E);
        float p3 = exp2f((s[qs][ct][3] - mnew) * L2E);
        ps += (p0 + p1) + (p2 + p3);
        unsigned short h0 = f2bf(p0), h1 = f2bf(p1), h2 = f2bf(p2), h3 = f2bf(p3);
        unsigned short l0 = f2bf(p0 - bf2f(h0)), l1 = f2bf(p1 - bf2f(h1));
        unsigned short l2 = f2bf(p2 - bf2f(h2)), l3 = f2bf(p3 - bf2f(h3));
        uint2 wh, wl;
        wh.x = (unsigned)h0 | ((unsigned)h1 << 16); wh.y = (unsigned)h2 | ((unsigned)h3 << 16);
        wl.x = (unsigned)l0 | ((unsigned)l1 << 16); wl.y = (unsigned)l2 | ((unsigned)l3 << 16);
        *(uint2*)&prow[ct * 16 + g * 4] = wh;
        *(uint2*)&prow[64 + ct * 16 + g * 4] = wl;
      }
      ps += __shfl_xor(ps, 16);
      ps += __shfl_xor(ps, 32);
      l[qs] = l[qs] * corr + ps;
#pragma unroll
      for (int dt = 0; dt < 3; dt++) acc[qs][dt] *= corr;
    }

    // ---- P B-frags (wave-private LDS, no barrier) ----
    bf16x8 pfh[2][2], pfl[2][2];
#pragma unroll
    for (int qs = 0; qs < 2; qs++) {
      const unsigned short* prow = &Pt[w][(qs * 16 + lq) * 144];
#pragma unroll
      for (int c = 0; c < 2; c++) {
        pfh[qs][c] = *(const bf16x8*)&prow[c * 32 + g * 8];
        pfl[qs][c] = *(const bf16x8*)&prow[64 + c * 32 + g * 8];
      }
    }
    // ---- PV: o^T = V^T * P^T ----
#pragma unroll
    for (int c = 0; c < 2; c++) {
      const int grp = (((c << 2) + g) ^ (lq & 7)) << 3;
#pragma unroll
      for (int dt = 0; dt < 3; dt++) {
        const int ro = (dt * 16 + lq) * 64 + grp;
        bf16x8 vfh = *(const bf16x8*)&Vh[ro];
        bf16x8 vfl = *(const bf16x8*)&Vl[ro];
#pragma unroll
        for (int qs = 0; qs < 2; qs++) {
          acc[qs][dt] = MFMA16(vfh, pfh[qs][c], acc[qs][dt]);
          acc[qs][dt] = MFMA16(vfl, pfh[qs][c], acc[qs][dt]);
          acc[qs][dt] = MFMA16(vfh, pfl[qs][c], acc[qs][dt]);
        }
      }
    }
  }

  // ---- epilogue ----
#pragma unroll
  for (int qs = 0; qs < 2; qs++) {
    const float invl = 1.f / l[qs];
    const int qg = qb * 64 + w * 32 + qs * 16 + lq;
    float* op = o + ((size_t)b * 2048 + qg) * 384 + hq * 48 + g * 4;
#pragma unroll
    for (int dt = 0; dt < 3; dt++) {
      float4 ov;
      ov.x = acc[qs][dt][0] * invl; ov.y = acc[qs][dt][1] * invl;
      ov.z = acc[qs][dt][2] * invl; ov.w = acc[qs][dt][3] * invl;
      *(float4*)(op + dt * 16) = ov;
    }
  }
#undef ISSUE_LOADS
}

// ============================================================
// O-projection (LoRA pre-folded) + residual -> out
// ============================================================
__global__ __launch_bounds__(256) void proj_kernel(const float* __restrict__ o,
    const float* __restrict__ x, const float* __restrict__ Woef,
    float* __restrict__ out) {
  __shared__ float ht[16][385];
  int row0 = blockIdx.x * 16;
  int tid = threadIdx.x;
  for (int i = tid; i < 16 * NC; i += 256) ht[i / NC][i % NC] = o[(size_t)row0 * NC + i];
  __syncthreads();
  int tx = tid & 63, ty = tid >> 6;
  float acc[4][6];
#pragma unroll
  for (int a = 0; a < 4; a++)
#pragma unroll
    for (int gg = 0; gg < 6; gg++) acc[a][gg] = 0.f;
  for (int c = 0; c < NC; c++) {
    float hv[4];
#pragma unroll
    for (int rr = 0; rr < 4; rr++) hv[rr] = ht[ty + rr * 4][c];
    const float* wrow = Woef + (size_t)c * NC;
#pragma unroll
    for (int gg = 0; gg < 6; gg++) {
      float w = wrow[gg * 64 + tx];
#pragma unroll
      for (int rr = 0; rr < 4; rr++) acc[rr][gg] += hv[rr] * w;
    }
  }
#pragma unroll
  for (int rr = 0; rr < 4; rr++) {
    size_t rowg = row0 + ty + rr * 4;
#pragma unroll
    for (int gg = 0; gg < 6; gg++) {
      int col = gg * 64 + tx;
      out[rowg * NC + col] = x[rowg * NC + col] + acc[rr][gg];
    }
  }
}

// ============================================================
// Router: wave per token
// ============================================================
__global__ __launch_bounds__(256) void router_kernel(const float* __restrict__ flat,
    const float* __restrict__ Wr, const float* __restrict__ br,
    float* __restrict__ probs, float* __restrict__ top1_val, int* __restrict__ top1_idx) {
  int tid = threadIdx.x;
  int lane = tid & 63, w = tid >> 6;
  int token = blockIdx.x * 4 + w;
  const float* fr = flat + (size_t)token * NC;
  float p0 = 0.f, p1 = 0.f, p2 = 0.f, p3 = 0.f;
  for (int c = lane; c < NC; c += 64) {
    float f = fr[c];
    const float4 wr = *(const float4*)(Wr + c * 4);
    p0 += f * wr.x; p1 += f * wr.y; p2 += f * wr.z; p3 += f * wr.w;
  }
#pragma unroll
  for (int off = 32; off > 0; off >>= 1) {
    p0 += __shfl_xor(p0, off); p1 += __shfl_xor(p1, off);
    p2 += __shfl_xor(p2, off); p3 += __shfl_xor(p3, off);
  }
  if (lane == 0) {
    float l0 = p0 + br[0], l1 = p1 + br[1], l2 = p2 + br[2], l3 = p3 + br[3];
    float mx = fmaxf(fmaxf(l0, l1), fmaxf(l2, l3));
    float e0 = expf(l0 - mx), e1 = expf(l1 - mx), e2 = expf(l2 - mx), e3 = expf(l3 - mx);
    float inv = 1.f / (e0 + e1 + e2 + e3);
    float q0 = e0 * inv, q1 = e1 * inv, q2 = e2 * inv, q3 = e3 * inv;
    probs[token * 4 + 0] = q0; probs[token * 4 + 1] = q1;
    probs[token * 4 + 2] = q2; probs[token * 4 + 3] = q3;
    int best = 0; float bv = q0;
    if (q1 > bv) { bv = q1; best = 1; }
    if (q2 > bv) { bv = q2; best = 2; }
    if (q3 > bv) { bv = q3; best = 3; }
    top1_idx[token] = best;
    top1_val[token] = bv;
  }
}

// ============================================================
// Scan: deterministic rank within expert (cumsum order), slot list, aux
// ============================================================
__global__ __launch_bounds__(256) void scan_kernel(const int* __restrict__ top1_idx,
    const float* __restrict__ probs, int* __restrict__ slot_token,
    float* __restrict__ aux_out) {
  __shared__ float psums[4];
  __shared__ int cnts[4][256];
  __shared__ int tot[4];
  int tid = threadIdx.x;
  int base = tid * 32;
  float s0 = 0.f, s1 = 0.f, s2 = 0.f, s3 = 0.f;
  int c0 = 0, c1 = 0, c2 = 0, c3 = 0;
  for (int i = 0; i < 32; i++) {
    int tk = base + i;
    s0 += probs[tk * 4 + 0]; s1 += probs[tk * 4 + 1];
    s2 += probs[tk * 4 + 2]; s3 += probs[tk * 4 + 3];
    int e = top1_idx[tk];
    if (e == 0) c0++; else if (e == 1) c1++; else if (e == 2) c2++; else c3++;
  }
  if (tid < 4) psums[tid] = 0.f;
  cnts[0][tid] = c0; cnts[1][tid] = c1; cnts[2][tid] = c2; cnts[3][tid] = c3;
  __syncthreads();
#pragma unroll
  for (int off = 32; off > 0; off >>= 1) {
    s0 += __shfl_xor(s0, off); s1 += __shfl_xor(s1, off);
    s2 += __shfl_xor(s2, off); s3 += __shfl_xor(s3, off);
  }
  if ((tid & 63) == 0) {
    atomicAdd(&psums[0], s0); atomicAdd(&psums[1], s1);
    atomicAdd(&psums[2], s2); atomicAdd(&psums[3], s3);
  }
  int w = tid >> 6, lane = tid & 63;
  int v0 = cnts[w][lane * 4 + 0], v1 = cnts[w][lane * 4 + 1];
  int v2 = cnts[w][lane * 4 + 2], v3 = cnts[w][lane * 4 + 3];
  int t4 = v0 + v1 + v2 + v3;
  int incl = t4;
#pragma unroll
  for (int off = 1; off < 64; off <<= 1) {
    int n = __shfl_up(incl, off);
    if (lane >= off) incl += n;
  }
  int excl = incl - t4;
  __syncthreads();
  cnts[w][lane * 4 + 0] = excl;
  cnts[w][lane * 4 + 1] = excl + v0;
  cnts[w][lane * 4 + 2] = excl + v0 + v1;
  cnts[w][lane * 4 + 3] = excl + v0 + v1 + v2;
  if (lane == 63) tot[w] = incl;
  __syncthreads();
  int pe0 = cnts[0][tid], pe1 = cnts[1][tid], pe2 = cnts[2][tid], pe3 = cnts[3][tid];
  for (int i = 0; i < 32; i++) {
    int tk = base + i;
    int e = top1_idx[tk];
    int r;
    if (e == 0) r = pe0++;
    else if (e == 1) r = pe1++;
    else if (e == 2) r = pe2++;
    else r = pe3++;
    if (r < NCAP) slot_token[e * NCAP + r] = tk;
  }
  __syncthreads();
  if (tid == 0) {
    float aux = 0.f;
#pragma unroll
    for (int e = 0; e < 4; e++) {
      int d = tot[e] < NCAP ? tot[e] : NCAP;
      aux += (psums[e] * (1.f / NTOKENS)) * ((float)d * (1.f / NTOKENS));
    }
    aux_out[0] = aux * (float)NEXP;
  }
}

// ============================================================
// Fused expert FFN: bf16 MFMA, LoRA pre-folded into W1T/W2T.
// ============================================================
__global__ __launch_bounds__(256) void ffn_mfma_kernel(const float* __restrict__ flat,
    const int* __restrict__ slot_token, const float* __restrict__ top1_val,
    const unsigned short* __restrict__ W1T, const unsigned short* __restrict__ W2T,
    float* __restrict__ out) {
  __shared__ unsigned short ft[32][384];
  __shared__ unsigned short hc[32][512];
  __shared__ int toks[32];
  __shared__ float gates[32];
  int e = blockIdx.y;
  int s0 = blockIdx.x * 32;
  int tid = threadIdx.x;
  int w = tid >> 6, lane = tid & 63;
  int row_a = lane & 15;
  int kgrp = lane >> 4;
  if (tid < 32) {
    int tk = slot_token[e * NCAP + s0 + tid];
    toks[tid] = tk;
    gates[tid] = (tk >= 0) ? top1_val[tk] : 0.f;
  }
  __syncthreads();
  if (toks[0] < 0) return;
  for (int i = tid; i < 32 * 384; i += 256) {
    int r = i / 384, c = i - r * 384;
    int tk = toks[r];
    float xv = (tk >= 0) ? flat[(size_t)tk * NC + c] : 0.f;
    ft[r][c] = f2bf(xv);
  }
  __syncthreads();
  f32x4 acc2[2][6];
#pragma unroll
  for (int mt = 0; mt < 2; mt++)
#pragma unroll
    for (int nt = 0; nt < 6; nt++) acc2[mt][nt] = (f32x4){0.f, 0.f, 0.f, 0.f};

  for (int ch = 0; ch < 3; ch++) {
#pragma unroll
    for (int mt = 0; mt < 2; mt++) {
      bf16x8 a[12];
#pragma unroll
      for (int kk = 0; kk < 12; kk++)
        a[kk] = *(const bf16x8*)&ft[mt * 16 + row_a][kk * 32 + kgrp * 8];
#pragma unroll
      for (int nt = 0; nt < 8; nt++) {
        int ncol = ch * 512 + w * 128 + nt * 16 + row_a;
        const unsigned short* bp = W1T + ((size_t)e * NFF + ncol) * NC;
        f32x4 c = (f32x4){0.f, 0.f, 0.f, 0.f};
#pragma unroll
        for (int kk = 0; kk < 12; kk++) {
          bf16x8 bf = *(const bf16x8*)(bp + kk * 32 + kgrp * 8);
          c = MFMA16(a[kk], bf, c);
        }
        int hcol = w * 128 + nt * 16 + row_a;
#pragma unroll
        for (int r = 0; r < 4; r++) {
          hc[mt * 16 + kgrp * 4 + r][hcol] = f2bf(fmaxf(c[r], 0.f));
        }
      }
    }
    __syncthreads();
#pragma unroll
    for (int mt = 0; mt < 2; mt++) {
      bf16x8 a2[16];
#pragma unroll
      for (int kk = 0; kk < 16; kk++)
        a2[kk] = *(const bf16x8*)&hc[mt * 16 + row_a][kk * 32 + kgrp * 8];
#pragma unroll
      for (int nt = 0; nt < 6; nt++) {
        int ncol = w * 96 + nt * 16 + row_a;
        const unsigned short* bp = W2T + ((size_t)e * NC + ncol) * NFF + ch * 512;
        f32x4 c = acc2[mt][nt];
#pragma unroll
        for (int kk = 0; kk < 16; kk++) {
          bf16x8 bf = *(const bf16x8*)(bp + kk * 32 + kgrp * 8);
          c = MFMA16(a2[kk], bf, c);
        }
        acc2[mt][nt] = c;
      }
    }
    __syncthreads();
  }
#pragma unroll
  for (int mt = 0; mt < 2; mt++) {
#pragma unroll
    for (int r = 0; r < 4; r++) {
      int srow = mt * 16 + kgrp * 4 + r;
      int tk = toks[srow];
      if (tk < 0) continue;
      float g = gates[srow];
#pragma unroll
      for (int nt = 0; nt < 6; nt++) {
        int col = w * 96 + nt * 16 + row_a;
        out[(size_t)tk * NC + col] += acc2[mt][nt][r] * g;
      }
    }
  }
}

// ============================================================
extern "C" void kernel_launch(void* const* d_in, const int* in_sizes, int n_in,
                              void* d_out, int out_size, void* d_ws, size_t ws_size,
                              hipStream_t stream) {
  const float* x   = (const float*)d_in[0];
  const int*   aid = (const int*)d_in[1];
  const float* ln1g = (const float*)d_in[2];
  const float* ln1b = (const float*)d_in[3];
  const float* ln2g = (const float*)d_in[4];
  const float* ln2b = (const float*)d_in[5];
  const float* Wq = (const float*)d_in[6];
  const float* Aq = (const float*)d_in[7];
  const float* Bq = (const float*)d_in[8];
  const float* Wk = (const float*)d_in[9];
  const float* Ak = (const float*)d_in[10];
  const float* Bk = (const float*)d_in[11];
  const float* Wv = (const float*)d_in[12];
  const float* Av = (const float*)d_in[13];
  const float* Bv = (const float*)d_in[14];
  const float* Wo = (const float*)d_in[15];
  const float* Ao = (const float*)d_in[16];
  const float* Bo = (const float*)d_in[17];
  const float* Wr = (const float*)d_in[18];
  const float* br = (const float*)d_in[19];
  const float* W1 = (const float*)d_in[20];
  const float* A1 = (const float*)d_in[21];
  const float* B1 = (const float*)d_in[22];
  const float* W2 = (const float*)d_in[23];
  const float* A2 = (const float*)d_in[24];
  const float* B2 = (const float*)d_in[25];
  float* out = (float*)d_out;
  float* ws = (float*)d_ws;

  float* h     = ws + OFF_H;
  float* flat  = ws + OFF_H;               // reused after attention
  float* q     = ws + OFF_Q;
  float* k     = ws + OFF_K;
  float* v     = ws + OFF_V;
  float* o     = ws + OFF_O;
  float* Woef  = ws + OFF_WOEF;
  unsigned short* W1T = (unsigned short*)(ws + OFF_W1T);
  unsigned short* W2T = (unsigned short*)(ws + OFF_W2T);
  float* Wpk   = ws + OFF_WPK;
  float* probs = ws + OFF_PROBS;
  float* t1v   = ws + OFF_T1V;
  int*   t1i   = (int*)(ws + OFF_T1I);
  int*   slot  = (int*)(ws + OFF_SLOT);

  // split-bf16 buffers in dead regions:
  unsigned short* qhi  = (unsigned short*)(ws + OFF_H);      // h dead after qkv
  unsigned short* qlo  = qhi + (size_t)65536 * 48;
  unsigned short* khi2 = (unsigned short*)(ws + OFF_Q);      // q fp32 dead after prep_q
  unsigned short* klo2 = khi2 + (size_t)16384 * 64;
  unsigned short* vthi = (unsigned short*)(ws + OFF_Q + 1048576);
  unsigned short* vtlo = vthi + (size_t)16384 * 48;

  pack_attn_kernel<<<1440, 256, 0, stream>>>(aid, Wq, Aq, Bq, Wk, Ak, Bk, Wv, Av, Bv,
                                             Wo, Ao, Bo, Wpk, Woef, slot);
  pack_w1t_kernel<<<dim3(24, 6, 4), 256, 0, stream>>>(aid, W1, A1, B1, W1T);
  pack_w2t_kernel<<<dim3(24, 6, 4), 256, 0, stream>>>(aid, W2, A2, B2, W2T);
  ln_kernel<<<NTOKENS / 4, 256, 0, stream>>>(x, ln1g, ln1b, h);
  qkv_kernel<<<NTOKENS / 16, 256, 0, stream>>>(h, Wpk, q, k, v);
  prep_q_kernel<<<256, 256, 0, stream>>>(q, qhi, qlo);          // after this, q fp32 dead
  prep_k_kernel<<<64, 256, 0, stream>>>(k, khi2, klo2);
  prep_v_kernel<<<dim3(32, 8), 256, 0, stream>>>(v, vthi, vtlo);
  attn_mfma_kernel<<<dim3(32, 32), 128, 0, stream>>>(qhi, qlo, khi2, klo2, vthi, vtlo, o);
  proj_kernel<<<NTOKENS / 16, 256, 0, stream>>>(o, x, Woef, out);
  ln_kernel<<<NTOKENS / 4, 256, 0, stream>>>(out, ln2g, ln2b, flat);
  router_kernel<<<NTOKENS / 4, 256, 0, stream>>>(flat, Wr, br, probs, t1v, t1i);
  scan_kernel<<<1, 256, 0, stream>>>(t1i, probs, slot, out + (size_t)NTOKENS * NC);
  ffn_mfma_kernel<<<dim3(NCAP / 32, NEXP), 256, 0, stream>>>(flat, slot, t1v, W1T, W2T, out);
}

// Round 5
// 693.970 us; speedup vs baseline: 3.3776x; 1.3643x over previous
//
#include <hip/hip_runtime.h>
#include <math.h>

// ---- problem constants ----
#define NC   384
#define NHQ  8
#define NHKV 2
#define NR   4
#define NEXP 4
#define NB   4
#define NT   2048
#define NTOKENS 8192
#define NCAP 2560
#define NFF  1536
#define NQKV 576
#define LORA_SCALE 0.25f
#define L2E 1.4426950408889634f
#define QSCALE 0.14433756729740643f

// ---- ws layout (byte offsets) ----
// region A [0,12.58M): hhi/hlo (ln1 split, dead after qkv) -> ohi/olo (attn out)
#define OB_HSPLIT_HI ((size_t)0)
#define OB_HSPLIT_LO ((size_t)6291456)
#define OB_QHI       ((size_t)12582912)
#define OB_QLO       ((size_t)18874368)
#define OB_KHI       ((size_t)25165824)
#define OB_KLO       ((size_t)26738688)
#define OB_VTHI      ((size_t)28311552)
#define OB_VTLO      ((size_t)29884416)
#define OB_FLAT      ((size_t)31457280)
#define OB_WPKT_HI   ((size_t)44040192)
#define OB_WPKT_LO   ((size_t)44482560)
#define OB_WOET_HI   ((size_t)44924928)
#define OB_WOET_LO   ((size_t)45219840)
#define OB_W1T       ((size_t)45514752)
#define OB_W2T       ((size_t)50233344)
#define OB_PROBS     ((size_t)54951936)
#define OB_T1V       ((size_t)55083008)
#define OB_T1I       ((size_t)55115776)
#define OB_SLOT      ((size_t)55148544)

typedef short bf16x8 __attribute__((ext_vector_type(8)));
typedef float f32x4  __attribute__((ext_vector_type(4)));

__device__ __forceinline__ unsigned short f2bf(float x) {
  union { float f; unsigned u; } a; a.f = x;
  unsigned r = a.u + 0x7FFFu + ((a.u >> 16) & 1u);
  return (unsigned short)(r >> 16);
}
__device__ __forceinline__ float bf2f(unsigned short h) {
  union { unsigned u; float f; } a; a.u = ((unsigned)h) << 16; return a.f;
}

#define MFMA16(a, b, c) __builtin_amdgcn_mfma_f32_16x16x32_bf16((a), (b), (c), 0, 0, 0)

// ============================================================
// LayerNorm -> split bf16 hi/lo (ln1)
// ============================================================
__global__ __launch_bounds__(256) void ln_split_kernel(const float* __restrict__ x,
    const float* __restrict__ g, const float* __restrict__ bb,
    unsigned short* __restrict__ ohi, unsigned short* __restrict__ olo) {
  int row = blockIdx.x * 4 + (threadIdx.x >> 6);
  int lane = threadIdx.x & 63;
  const float* xr = x + (size_t)row * NC;
  float v0[6];
  float s = 0.f;
#pragma unroll
  for (int i = 0; i < 6; i++) { v0[i] = xr[lane + i * 64]; s += v0[i]; }
#pragma unroll
  for (int o = 32; o > 0; o >>= 1) s += __shfl_xor(s, o);
  float mean = s * (1.f / NC);
  float s2 = 0.f;
#pragma unroll
  for (int i = 0; i < 6; i++) { float d = v0[i] - mean; s2 += d * d; }
#pragma unroll
  for (int o = 32; o > 0; o >>= 1) s2 += __shfl_xor(s2, o);
  float rstd = rsqrtf(s2 * (1.f / NC) + 1e-5f);
#pragma unroll
  for (int i = 0; i < 6; i++) {
    int c = lane + i * 64;
    float val = (v0[i] - mean) * rstd * g[c] + bb[c];
    unsigned short h = f2bf(val);
    ohi[(size_t)row * NC + c] = h;
    olo[(size_t)row * NC + c] = f2bf(val - bf2f(h));
  }
}

// ============================================================
// LayerNorm -> f32 (ln2)
// ============================================================
__global__ __launch_bounds__(256) void ln_kernel(const float* __restrict__ x,
    const float* __restrict__ g, const float* __restrict__ bb,
    float* __restrict__ out) {
  int row = blockIdx.x * 4 + (threadIdx.x >> 6);
  int lane = threadIdx.x & 63;
  const float* xr = x + (size_t)row * NC;
  float v0[6];
  float s = 0.f;
#pragma unroll
  for (int i = 0; i < 6; i++) { v0[i] = xr[lane + i * 64]; s += v0[i]; }
#pragma unroll
  for (int o = 32; o > 0; o >>= 1) s += __shfl_xor(s, o);
  float mean = s * (1.f / NC);
  float s2 = 0.f;
#pragma unroll
  for (int i = 0; i < 6; i++) { float d = v0[i] - mean; s2 += d * d; }
#pragma unroll
  for (int o = 32; o > 0; o >>= 1) s2 += __shfl_xor(s2, o);
  float rstd = rsqrtf(s2 * (1.f / NC) + 1e-5f);
  float* orow = out + (size_t)row * NC;
#pragma unroll
  for (int i = 0; i < 6; i++) {
    int c = lane + i * 64;
    orow[c] = (v0[i] - mean) * rstd * g[c] + bb[c];
  }
}

// ============================================================
// Pack attn weights: fold LoRA, TRANSPOSE, split bf16 hi/lo.
// Wpkt[col=576][c=384], Woet[col=384][c=384]. Init slot=-1.
// ============================================================
__global__ __launch_bounds__(256) void pack_attn_kernel(const int* __restrict__ aidp,
    const float* __restrict__ Wq, const float* __restrict__ Aq, const float* __restrict__ Bq,
    const float* __restrict__ Wk, const float* __restrict__ Ak, const float* __restrict__ Bk,
    const float* __restrict__ Wv, const float* __restrict__ Av, const float* __restrict__ Bv,
    const float* __restrict__ Wo, const float* __restrict__ Ao, const float* __restrict__ Bo,
    unsigned short* __restrict__ wpkt_hi, unsigned short* __restrict__ wpkt_lo,
    unsigned short* __restrict__ woet_hi, unsigned short* __restrict__ woet_lo,
    int* __restrict__ slot_token) {
  int aid = aidp[0];
  int idx = blockIdx.x * 256 + threadIdx.x;
  if (idx < NC * NQKV) {
    int c = idx / NQKV, col = idx % NQKV;
    float w; const float* A; const float* B; int loc;
    if (col < 384)      { w = Wq[c * 384 + col];        A = Aq; B = Bq; loc = col; }
    else if (col < 480) { w = Wk[c * 96 + (col - 384)]; A = Ak; B = Bk; loc = col - 384; }
    else                { w = Wv[c * 96 + (col - 480)]; A = Av; B = Bv; loc = col - 480; }
    float s = 0.f;
#pragma unroll
    for (int r = 0; r < 4; r++)
      s += A[((size_t)aid * 4 + r) * NC + c] * B[((size_t)(col < 384 ? aid * 384 : aid * 96) + loc) * 4 + r];
    float val = w + LORA_SCALE * s;
    unsigned short h = f2bf(val);
    size_t tix = (size_t)col * NC + c;
    wpkt_hi[tix] = h; wpkt_lo[tix] = f2bf(val - bf2f(h));
  }
  int j = idx - NC * NQKV;
  if (j >= 0 && j < NC * NC) {
    int c = j / NC, col = j % NC;
    float s = 0.f;
#pragma unroll
    for (int r = 0; r < 4; r++)
      s += Ao[((size_t)aid * 4 + r) * NC + c] * Bo[((size_t)aid * NC + col) * 4 + r];
    float val = Wo[(size_t)c * NC + col] + LORA_SCALE * s;
    unsigned short h = f2bf(val);
    size_t tix = (size_t)col * NC + c;
    woet_hi[tix] = h; woet_lo[tix] = f2bf(val - bf2f(h));
  }
  if (idx < NEXP * NCAP) slot_token[idx] = -1;
}

// ============================================================
// Pack W1 -> W1T bf16 [E][F][C] with LoRA folded
// ============================================================
__global__ __launch_bounds__(256) void pack_w1t_kernel(const int* __restrict__ aidp,
    const float* __restrict__ W1, const float* __restrict__ A1, const float* __restrict__ B1,
    unsigned short* __restrict__ W1T) {
  __shared__ float tile[64][65];
  int aid = aidp[0];
  int e = blockIdx.z, cb = blockIdx.y, fb = blockIdx.x;
  int tid = threadIdx.x;
  int tlo = tid & 63, thi = tid >> 6;
  size_t la = ((size_t)e * 4 + aid);
#pragma unroll
  for (int ii = 0; ii < 16; ii++) {
    int c = cb * 64 + ii * 4 + thi;
    int f = fb * 64 + tlo;
    float val = W1[((size_t)e * NC + c) * NFF + f];
    float s = 0.f;
#pragma unroll
    for (int r = 0; r < 4; r++)
      s += A1[(la * 4 + r) * NC + c] * B1[(la * NFF + f) * 4 + r];
    tile[ii * 4 + thi][tlo] = val + LORA_SCALE * s;
  }
  __syncthreads();
#pragma unroll
  for (int ii = 0; ii < 16; ii++) {
    int floc = ii * 4 + thi;
    W1T[((size_t)e * NFF + fb * 64 + floc) * NC + cb * 64 + tlo] = f2bf(tile[tlo][floc]);
  }
}

// ============================================================
// Pack W2 -> W2T bf16 [E][C][F] with LoRA folded
// ============================================================
__global__ __launch_bounds__(256) void pack_w2t_kernel(const int* __restrict__ aidp,
    const float* __restrict__ W2, const float* __restrict__ A2, const float* __restrict__ B2,
    unsigned short* __restrict__ W2T) {
  __shared__ float tile[64][65];
  int aid = aidp[0];
  int e = blockIdx.z, cb = blockIdx.y, fb = blockIdx.x;
  int tid = threadIdx.x;
  int tlo = tid & 63, thi = tid >> 6;
  size_t la = ((size_t)e * 4 + aid);
#pragma unroll
  for (int ii = 0; ii < 16; ii++) {
    int f = fb * 64 + ii * 4 + thi;
    int c = cb * 64 + tlo;
    float val = W2[((size_t)e * NFF + f) * NC + c];
    float s = 0.f;
#pragma unroll
    for (int r = 0; r < 4; r++)
      s += A2[(la * 4 + r) * NFF + f] * B2[(la * NC + c) * 4 + r];
    tile[ii * 4 + thi][tlo] = val + LORA_SCALE * s;
  }
  __syncthreads();
#pragma unroll
  for (int ii = 0; ii < 16; ii++) {
    int cloc = ii * 4 + thi;
    W2T[((size_t)e * NC + cb * 64 + cloc) * NFF + fb * 64 + tlo] = f2bf(tile[tlo][cloc]);
  }
}

// ============================================================
// QKV split-bf16 MFMA GEMM (8192x384 @ 384x576) with fused
// RoPE+scale+split epilogue, scattering to q/k/vT split layouts.
// grid 512 blocks x 256 thr; wave w covers n-cols [w*144, w*144+144).
// ============================================================
__global__ __launch_bounds__(256) void qkv_mfma_kernel(
    const unsigned short* __restrict__ hhi, const unsigned short* __restrict__ hlo,
    const unsigned short* __restrict__ wthi, const unsigned short* __restrict__ wtlo,
    unsigned short* __restrict__ qhi, unsigned short* __restrict__ qlo,
    unsigned short* __restrict__ khi, unsigned short* __restrict__ klo,
    unsigned short* __restrict__ vthi, unsigned short* __restrict__ vtlo) {
  const int m0 = blockIdx.x * 16;
  const int tid = threadIdx.x;
  const int w = tid >> 6, lane = tid & 63;
  const int lq = lane & 15, g = lane >> 4;
  bf16x8 ah[12], al[12];
  const unsigned short* arow_h = hhi + (size_t)(m0 + lq) * NC;
  const unsigned short* arow_l = hlo + (size_t)(m0 + lq) * NC;
#pragma unroll
  for (int kk = 0; kk < 12; kk++) {
    ah[kk] = *(const bf16x8*)(arow_h + kk * 32 + g * 8);
    al[kk] = *(const bf16x8*)(arow_l + kk * 32 + g * 8);
  }
#pragma unroll
  for (int nt = 0; nt < 9; nt++) {
    const int ncol = w * 144 + nt * 16 + lq;
    const int colbase = w * 144 + nt * 16;     // wave-uniform category
    const unsigned short* bp_h = wthi + (size_t)ncol * NC;
    const unsigned short* bp_l = wtlo + (size_t)ncol * NC;
    f32x4 c = (f32x4){0.f, 0.f, 0.f, 0.f};
#pragma unroll
    for (int kk = 0; kk < 12; kk++) {
      bf16x8 bh = *(const bf16x8*)(bp_h + kk * 32 + g * 8);
      bf16x8 bl = *(const bf16x8*)(bp_l + kk * 32 + g * 8);
      c = MFMA16(ah[kk], bh, c);
      c = MFMA16(al[kk], bh, c);
      c = MFMA16(ah[kk], bl, c);
    }
    if (colbase < 480) {                       // q or k: rope
      const int dloc = ncol % 48;
      const int j = dloc >> 1;
      const int parity = ncol & 1;
      const bool isq = colbase < 384;
      const float scale = isq ? QSCALE : 1.f;
      const float inv = powf(10000.f, -(float)(2 * j) * (1.f / 48.f));
#pragma unroll
      for (int r = 0; r < 4; r++) {
        int row = m0 + g * 4 + r;
        int t = row & (NT - 1);
        int bb = row >> 11;
        float sn, cs; sincosf((float)t * inv, &sn, &cs);
        float pv = __shfl_xor(c[r], 1);
        float roped = (c[r] * cs + (parity ? pv * sn : -pv * sn)) * scale;
        unsigned short h_ = f2bf(roped);
        unsigned short l_ = f2bf(roped - bf2f(h_));
        size_t idx;
        if (isq) {
          idx = ((size_t)(bb * NHQ + ncol / 48) * NT + t) * 48 + dloc;
          qhi[idx] = h_; qlo[idx] = l_;
        } else {
          int ck = ncol - 384;
          idx = ((size_t)(bb * NHKV + ck / 48) * NT + t) * 48 + (ck % 48);
          khi[idx] = h_; klo[idx] = l_;
        }
      }
    } else {                                   // v: transpose store
      const int cv = ncol - 480;
      const int hh = cv / 48, dloc = cv % 48;
#pragma unroll
      for (int r = 0; r < 4; r++) {
        int row = m0 + g * 4 + r;
        int t = row & (NT - 1);
        int bb = row >> 11;
        float val = c[r];
        unsigned short h_ = f2bf(val);
        unsigned short l_ = f2bf(val - bf2f(h_));
        size_t idx = ((size_t)(bb * NHKV + hh) * 48 + dloc) * NT + t;
        vthi[idx] = h_; vtlo[idx] = l_;
      }
    }
  }
}

// ============================================================
// Flash attention, split-bf16 MFMA, NO K/V LDS staging (L2-resident
// direct frag loads). Only P goes through wave-private swizzled LDS.
// 128 thr (2 waves x 32q), K-tile 64, no __syncthreads at all.
// ============================================================
__global__ __launch_bounds__(128) void attn_mfma_kernel(
    const unsigned short* __restrict__ qhi, const unsigned short* __restrict__ qlo,
    const unsigned short* __restrict__ khi, const unsigned short* __restrict__ klo,
    const unsigned short* __restrict__ vthi, const unsigned short* __restrict__ vtlo,
    unsigned short* __restrict__ ohi, unsigned short* __restrict__ olo) {
  __shared__ unsigned short Pt[2][4096];   // per-wave [32 rows][128]: 16B units, XOR-swizzled
  const int qb = 31 - (int)blockIdx.x;
  const int bh = blockIdx.y;
  const int b = bh >> 3, hq = bh & 7, hk = hq >> 2;
  const int bhk = b * NHKV + hk;
  const int tid = threadIdx.x;
  const int w = tid >> 6, lane = tid & 63;
  const int lq = lane & 15, g = lane >> 4;
  const int sw = lq & 7;
  unsigned short* PtW = Pt[w];
  const bf16x8 zf = {0, 0, 0, 0, 0, 0, 0, 0};

  bf16x8 qfh[2][2], qfl[2][2];
#pragma unroll
  for (int qs = 0; qs < 2; qs++) {
    size_t qoff = ((size_t)bh * NT + qb * 64 + w * 32 + qs * 16 + lq) * 48;
    qfh[qs][0] = *(const bf16x8*)(qhi + qoff + g * 8);
    qfl[qs][0] = *(const bf16x8*)(qlo + qoff + g * 8);
    qfh[qs][1] = (g < 2) ? *(const bf16x8*)(qhi + qoff + 32 + g * 8) : zf;
    qfl[qs][1] = (g < 2) ? *(const bf16x8*)(qlo + qoff + 32 + g * 8) : zf;
  }
  f32x4 acc[2][3];
#pragma unroll
  for (int qs = 0; qs < 2; qs++)
#pragma unroll
    for (int dt = 0; dt < 3; dt++) acc[qs][dt] = (f32x4){0.f, 0.f, 0.f, 0.f};
  float m[2] = {-1e30f, -1e30f}, l[2] = {0.f, 0.f};

  const unsigned short* kb_h = khi + (size_t)bhk * NT * 48;
  const unsigned short* kb_l = klo + (size_t)bhk * NT * 48;
  const unsigned short* vb_h = vthi + (size_t)bhk * 48 * NT;
  const unsigned short* vb_l = vtlo + (size_t)bhk * 48 * NT;

  for (int kt = 0; kt <= qb; kt++) {
    // ---- QK: s^T = K * Q^T ----
    f32x4 s[2][4];
#pragma unroll
    for (int qs = 0; qs < 2; qs++)
#pragma unroll
      for (int ct = 0; ct < 4; ct++) s[qs][ct] = (f32x4){0.f, 0.f, 0.f, 0.f};
#pragma unroll
    for (int ct = 0; ct < 4; ct++) {
      const size_t ko = (size_t)(kt * 64 + ct * 16 + lq) * 48;
      bf16x8 kh0 = *(const bf16x8*)(kb_h + ko + g * 8);
      bf16x8 kl0 = *(const bf16x8*)(kb_l + ko + g * 8);
      bf16x8 kh1 = (g < 2) ? *(const bf16x8*)(kb_h + ko + 32 + g * 8) : zf;
      bf16x8 kl1 = (g < 2) ? *(const bf16x8*)(kb_l + ko + 32 + g * 8) : zf;
#pragma unroll
      for (int qs = 0; qs < 2; qs++) {
        s[qs][ct] = MFMA16(kh0, qfh[qs][0], s[qs][ct]);
        s[qs][ct] = MFMA16(kl0, qfh[qs][0], s[qs][ct]);
        s[qs][ct] = MFMA16(kh0, qfl[qs][0], s[qs][ct]);
        s[qs][ct] = MFMA16(kh1, qfh[qs][1], s[qs][ct]);
        s[qs][ct] = MFMA16(kl1, qfh[qs][1], s[qs][ct]);
        s[qs][ct] = MFMA16(kh1, qfl[qs][1], s[qs][ct]);
      }
    }
    // ---- causal mask on diagonal tile ----
    if (kt == qb) {
#pragma unroll
      for (int qs = 0; qs < 2; qs++) {
        const int qg = qb * 64 + w * 32 + qs * 16 + lq;
#pragma unroll
        for (int ct = 0; ct < 4; ct++) {
          const int k0 = kt * 64 + ct * 16 + g * 4;
#pragma unroll
          for (int r = 0; r < 4; r++)
            if (k0 + r > qg) s[qs][ct][r] = -1e30f;
        }
      }
    }
    // ---- online softmax (lane owns q-row), write P hi/lo to swizzled LDS ----
#pragma unroll
    for (int qs = 0; qs < 2; qs++) {
      float mx = s[qs][0][0];
#pragma unroll
      for (int ct = 0; ct < 4; ct++)
#pragma unroll
        for (int r = 0; r < 4; r++) mx = fmaxf(mx, s[qs][ct][r]);
      mx = fmaxf(mx, __shfl_xor(mx, 16));
      mx = fmaxf(mx, __shfl_xor(mx, 32));
      const float mnew = fmaxf(m[qs], mx);
      const float corr = exp2f((m[qs] - mnew) * L2E);
      m[qs] = mnew;
      float ps = 0.f;
      unsigned short* prow = PtW + (qs * 16 + lq) * 128;
#pragma unroll
      for (int ct = 0; ct < 4; ct++) {
        float p0 = exp2f((s[qs][ct][0] - mnew) * L2E);
        float p1 = exp2f((s[qs][ct][1] - mnew) * L2E);
        float p2 = exp2f((s[qs][ct][2] - mnew) * L2E);
        float p3 = exp2f((s[qs][ct][3] - mnew) * L2E);
        ps += (p0 + p1) + (p2 + p3);
        unsigned short h0 = f2bf(p0), h1 = f2bf(p1), h2 = f2bf(p2), h3 = f2bf(p3);
        unsigned short l0 = f2bf(p0 - bf2f(h0)), l1 = f2bf(p1 - bf2f(h1));
        unsigned short l2 = f2bf(p2 - bf2f(h2)), l3 = f2bf(p3 - bf2f(h3));
        uint2 wh, wl;
        wh.x = (unsigned)h0 | ((unsigned)h1 << 16); wh.y = (unsigned)h2 | ((unsigned)h3 << 16);
        wl.x = (unsigned)l0 | ((unsigned)l1 << 16); wl.y = (unsigned)l2 | ((unsigned)l3 << 16);
        const int u = ct * 2 + (g >> 1), sub = (g & 1) * 4;
        *(uint2*)&prow[((u ^ sw) << 3) + sub] = wh;
        *(uint2*)&prow[(((8 + u) ^ sw) << 3) + sub] = wl;
      }
      ps += __shfl_xor(ps, 16);
      ps += __shfl_xor(ps, 32);
      l[qs] = l[qs] * corr + ps;
#pragma unroll
      for (int dt = 0; dt < 3; dt++) acc[qs][dt] *= corr;
    }
    // ---- P B-frags from wave-private LDS (no barrier) ----
    bf16x8 pfh[2][2], pfl[2][2];
#pragma unroll
    for (int qs = 0; qs < 2; qs++) {
      const unsigned short* prow = PtW + (qs * 16 + lq) * 128;
#pragma unroll
      for (int c = 0; c < 2; c++) {
        pfh[qs][c] = *(const bf16x8*)&prow[((c * 4 + g) ^ sw) << 3];
        pfl[qs][c] = *(const bf16x8*)&prow[((8 + c * 4 + g) ^ sw) << 3];
      }
    }
    // ---- PV: o^T = V^T * P^T ----
#pragma unroll
    for (int dt = 0; dt < 3; dt++) {
      const size_t vo = (size_t)(dt * 16 + lq) * NT + kt * 64;
      bf16x8 vh0 = *(const bf16x8*)(vb_h + vo + g * 8);
      bf16x8 vl0 = *(const bf16x8*)(vb_l + vo + g * 8);
      bf16x8 vh1 = *(const bf16x8*)(vb_h + vo + 32 + g * 8);
      bf16x8 vl1 = *(const bf16x8*)(vb_l + vo + 32 + g * 8);
#pragma unroll
      for (int qs = 0; qs < 2; qs++) {
        acc[qs][dt] = MFMA16(vh0, pfh[qs][0], acc[qs][dt]);
        acc[qs][dt] = MFMA16(vl0, pfh[qs][0], acc[qs][dt]);
        acc[qs][dt] = MFMA16(vh0, pfl[qs][0], acc[qs][dt]);
        acc[qs][dt] = MFMA16(vh1, pfh[qs][1], acc[qs][dt]);
        acc[qs][dt] = MFMA16(vl1, pfh[qs][1], acc[qs][dt]);
        acc[qs][dt] = MFMA16(vh1, pfl[qs][1], acc[qs][dt]);
      }
    }
  }
  // ---- epilogue: write o split bf16 ----
#pragma unroll
  for (int qs = 0; qs < 2; qs++) {
    const float invl = 1.f / l[qs];
    const int qg = qb * 64 + w * 32 + qs * 16 + lq;
    const size_t base = ((size_t)b * NT + qg) * NC + hq * 48 + g * 4;
#pragma unroll
    for (int dt = 0; dt < 3; dt++) {
      unsigned short h4[4], l4[4];
#pragma unroll
      for (int r = 0; r < 4; r++) {
        float v = acc[qs][dt][r] * invl;
        h4[r] = f2bf(v);
        l4[r] = f2bf(v - bf2f(h4[r]));
      }
      uint2 wh, wl;
      wh.x = (unsigned)h4[0] | ((unsigned)h4[1] << 16); wh.y = (unsigned)h4[2] | ((unsigned)h4[3] << 16);
      wl.x = (unsigned)l4[0] | ((unsigned)l4[1] << 16); wl.y = (unsigned)l4[2] | ((unsigned)l4[3] << 16);
      *(uint2*)(ohi + base + dt * 16) = wh;
      *(uint2*)(olo + base + dt * 16) = wl;
    }
  }
}

// ============================================================
// O-projection split-bf16 MFMA + residual: out = x + osplit @ Woet
// grid 512 x 256 thr; wave w covers cols [w*96, w*96+96).
// ============================================================
__global__ __launch_bounds__(256) void proj_mfma_kernel(
    const unsigned short* __restrict__ ohi, const unsigned short* __restrict__ olo,
    const unsigned short* __restrict__ wthi, const unsigned short* __restrict__ wtlo,
    const float* __restrict__ x, float* __restrict__ out) {
  const int m0 = blockIdx.x * 16;
  const int tid = threadIdx.x;
  const int w = tid >> 6, lane = tid & 63;
  const int lq = lane & 15, g = lane >> 4;
  bf16x8 ah[12], al[12];
  const unsigned short* arow_h = ohi + (size_t)(m0 + lq) * NC;
  const unsigned short* arow_l = olo + (size_t)(m0 + lq) * NC;
#pragma unroll
  for (int kk = 0; kk < 12; kk++) {
    ah[kk] = *(const bf16x8*)(arow_h + kk * 32 + g * 8);
    al[kk] = *(const bf16x8*)(arow_l + kk * 32 + g * 8);
  }
#pragma unroll
  for (int nt = 0; nt < 6; nt++) {
    const int ncol = w * 96 + nt * 16 + lq;
    const unsigned short* bp_h = wthi + (size_t)ncol * NC;
    const unsigned short* bp_l = wtlo + (size_t)ncol * NC;
    f32x4 c = (f32x4){0.f, 0.f, 0.f, 0.f};
#pragma unroll
    for (int kk = 0; kk < 12; kk++) {
      bf16x8 bh = *(const bf16x8*)(bp_h + kk * 32 + g * 8);
      bf16x8 bl = *(const bf16x8*)(bp_l + kk * 32 + g * 8);
      c = MFMA16(ah[kk], bh, c);
      c = MFMA16(al[kk], bh, c);
      c = MFMA16(ah[kk], bl, c);
    }
#pragma unroll
    for (int r = 0; r < 4; r++) {
      size_t row = m0 + g * 4 + r;
      out[row * NC + ncol] = x[row * NC + ncol] + c[r];
    }
  }
}

// ============================================================
// Router: wave per token
// ============================================================
__global__ __launch_bounds__(256) void router_kernel(const float* __restrict__ flat,
    const float* __restrict__ Wr, const float* __restrict__ br,
    float* __restrict__ probs, float* __restrict__ top1_val, int* __restrict__ top1_idx) {
  int tid = threadIdx.x;
  int lane = tid & 63, w = tid >> 6;
  int token = blockIdx.x * 4 + w;
  const float* fr = flat + (size_t)token * NC;
  float p0 = 0.f, p1 = 0.f, p2 = 0.f, p3 = 0.f;
  for (int c = lane; c < NC; c += 64) {
    float f = fr[c];
    const float4 wr = *(const float4*)(Wr + c * 4);
    p0 += f * wr.x; p1 += f * wr.y; p2 += f * wr.z; p3 += f * wr.w;
  }
#pragma unroll
  for (int off = 32; off > 0; off >>= 1) {
    p0 += __shfl_xor(p0, off); p1 += __shfl_xor(p1, off);
    p2 += __shfl_xor(p2, off); p3 += __shfl_xor(p3, off);
  }
  if (lane == 0) {
    float l0 = p0 + br[0], l1 = p1 + br[1], l2 = p2 + br[2], l3 = p3 + br[3];
    float mx = fmaxf(fmaxf(l0, l1), fmaxf(l2, l3));
    float e0 = expf(l0 - mx), e1 = expf(l1 - mx), e2 = expf(l2 - mx), e3 = expf(l3 - mx);
    float inv = 1.f / (e0 + e1 + e2 + e3);
    float q0 = e0 * inv, q1 = e1 * inv, q2 = e2 * inv, q3 = e3 * inv;
    probs[token * 4 + 0] = q0; probs[token * 4 + 1] = q1;
    probs[token * 4 + 2] = q2; probs[token * 4 + 3] = q3;
    int best = 0; float bv = q0;
    if (q1 > bv) { bv = q1; best = 1; }
    if (q2 > bv) { bv = q2; best = 2; }
    if (q3 > bv) { bv = q3; best = 3; }
    top1_idx[token] = best;
    top1_val[token] = bv;
  }
}

// ============================================================
// Scan: deterministic rank within expert (cumsum order), slot list, aux
// ============================================================
__global__ __launch_bounds__(256) void scan_kernel(const int* __restrict__ top1_idx,
    const float* __restrict__ probs, int* __restrict__ slot_token,
    float* __restrict__ aux_out) {
  __shared__ float psums[4];
  __shared__ int cnts[4][256];
  __shared__ int tot[4];
  int tid = threadIdx.x;
  int base = tid * 32;
  float s0 = 0.f, s1 = 0.f, s2 = 0.f, s3 = 0.f;
  int c0 = 0, c1 = 0, c2 = 0, c3 = 0;
  for (int i = 0; i < 32; i++) {
    int tk = base + i;
    s0 += probs[tk * 4 + 0]; s1 += probs[tk * 4 + 1];
    s2 += probs[tk * 4 + 2]; s3 += probs[tk * 4 + 3];
    int e = top1_idx[tk];
    if (e == 0) c0++; else if (e == 1) c1++; else if (e == 2) c2++; else c3++;
  }
  if (tid < 4) psums[tid] = 0.f;
  cnts[0][tid] = c0; cnts[1][tid] = c1; cnts[2][tid] = c2; cnts[3][tid] = c3;
  __syncthreads();
#pragma unroll
  for (int off = 32; off > 0; off >>= 1) {
    s0 += __shfl_xor(s0, off); s1 += __shfl_xor(s1, off);
    s2 += __shfl_xor(s2, off); s3 += __shfl_xor(s3, off);
  }
  if ((tid & 63) == 0) {
    atomicAdd(&psums[0], s0); atomicAdd(&psums[1], s1);
    atomicAdd(&psums[2], s2); atomicAdd(&psums[3], s3);
  }
  int w = tid >> 6, lane = tid & 63;
  int v0 = cnts[w][lane * 4 + 0], v1 = cnts[w][lane * 4 + 1];
  int v2 = cnts[w][lane * 4 + 2], v3 = cnts[w][lane * 4 + 3];
  int t4 = v0 + v1 + v2 + v3;
  int incl = t4;
#pragma unroll
  for (int off = 1; off < 64; off <<= 1) {
    int n = __shfl_up(incl, off);
    if (lane >= off) incl += n;
  }
  int excl = incl - t4;
  __syncthreads();
  cnts[w][lane * 4 + 0] = excl;
  cnts[w][lane * 4 + 1] = excl + v0;
  cnts[w][lane * 4 + 2] = excl + v0 + v1;
  cnts[w][lane * 4 + 3] = excl + v0 + v1 + v2;
  if (lane == 63) tot[w] = incl;
  __syncthreads();
  int pe0 = cnts[0][tid], pe1 = cnts[1][tid], pe2 = cnts[2][tid], pe3 = cnts[3][tid];
  for (int i = 0; i < 32; i++) {
    int tk = base + i;
    int e = top1_idx[tk];
    int r;
    if (e == 0) r = pe0++;
    else if (e == 1) r = pe1++;
    else if (e == 2) r = pe2++;
    else r = pe3++;
    if (r < NCAP) slot_token[e * NCAP + r] = tk;
  }
  __syncthreads();
  if (tid == 0) {
    float aux = 0.f;
#pragma unroll
    for (int e = 0; e < 4; e++) {
      int d = tot[e] < NCAP ? tot[e] : NCAP;
      aux += (psums[e] * (1.f / NTOKENS)) * ((float)d * (1.f / NTOKENS));
    }
    aux_out[0] = aux * (float)NEXP;
  }
}

// ============================================================
// Fused expert FFN: bf16 MFMA, LoRA pre-folded. Padded LDS strides
// (392/520 shorts: bank stride 4 mod 32 -> 2-way instead of 16-way).
// ============================================================
__global__ __launch_bounds__(256) void ffn_mfma_kernel(const float* __restrict__ flat,
    const int* __restrict__ slot_token, const float* __restrict__ top1_val,
    const unsigned short* __restrict__ W1T, const unsigned short* __restrict__ W2T,
    float* __restrict__ out) {
  __shared__ unsigned short ft[32][392];
  __shared__ unsigned short hc[32][520];
  __shared__ int toks[32];
  __shared__ float gates[32];
  int e = blockIdx.y;
  int s0 = blockIdx.x * 32;
  int tid = threadIdx.x;
  int w = tid >> 6, lane = tid & 63;
  int row_a = lane & 15;
  int kgrp = lane >> 4;
  if (tid < 32) {
    int tk = slot_token[e * NCAP + s0 + tid];
    toks[tid] = tk;
    gates[tid] = (tk >= 0) ? top1_val[tk] : 0.f;
  }
  __syncthreads();
  if (toks[0] < 0) return;
  for (int i = tid; i < 32 * 384; i += 256) {
    int r = i / 384, c = i - r * 384;
    int tk = toks[r];
    float xv = (tk >= 0) ? flat[(size_t)tk * NC + c] : 0.f;
    ft[r][c] = f2bf(xv);
  }
  __syncthreads();
  f32x4 acc2[2][6];
#pragma unroll
  for (int mt = 0; mt < 2; mt++)
#pragma unroll
    for (int nt = 0; nt < 6; nt++) acc2[mt][nt] = (f32x4){0.f, 0.f, 0.f, 0.f};

  for (int ch = 0; ch < 3; ch++) {
#pragma unroll
    for (int mt = 0; mt < 2; mt++) {
      bf16x8 a[12];
#pragma unroll
      for (int kk = 0; kk < 12; kk++)
        a[kk] = *(const bf16x8*)&ft[mt * 16 + row_a][kk * 32 + kgrp * 8];
#pragma unroll
      for (int nt = 0; nt < 8; nt++) {
        int ncol = ch * 512 + w * 128 + nt * 16 + row_a;
        const unsigned short* bp = W1T + ((size_t)e * NFF + ncol) * NC;
        f32x4 c = (f32x4){0.f, 0.f, 0.f, 0.f};
#pragma unroll
        for (int kk = 0; kk < 12; kk++) {
          bf16x8 bf = *(const bf16x8*)(bp + kk * 32 + kgrp * 8);
          c = MFMA16(a[kk], bf, c);
        }
        int hcol = w * 128 + nt * 16 + row_a;
#pragma unroll
        for (int r = 0; r < 4; r++) {
          hc[mt * 16 + kgrp * 4 + r][hcol] = f2bf(fmaxf(c[r], 0.f));
        }
      }
    }
    __syncthreads();
#pragma unroll
    for (int mt = 0; mt < 2; mt++) {
      bf16x8 a2[16];
#pragma unroll
      for (int kk = 0; kk < 16; kk++)
        a2[kk] = *(const bf16x8*)&hc[mt * 16 + row_a][kk * 32 + kgrp * 8];
#pragma unroll
      for (int nt = 0; nt < 6; nt++) {
        int ncol = w * 96 + nt * 16 + row_a;
        const unsigned short* bp = W2T + ((size_t)e * NC + ncol) * NFF + ch * 512;
        f32x4 c = acc2[mt][nt];
#pragma unroll
        for (int kk = 0; kk < 16; kk++) {
          bf16x8 bf = *(const bf16x8*)(bp + kk * 32 + kgrp * 8);
          c = MFMA16(a2[kk], bf, c);
        }
        acc2[mt][nt] = c;
      }
    }
    __syncthreads();
  }
#pragma unroll
  for (int mt = 0; mt < 2; mt++) {
#pragma unroll
    for (int r = 0; r < 4; r++) {
      int srow = mt * 16 + kgrp * 4 + r;
      int tk = toks[srow];
      if (tk < 0) continue;
      float g = gates[srow];
#pragma unroll
      for (int nt = 0; nt < 6; nt++) {
        int col = w * 96 + nt * 16 + row_a;
        out[(size_t)tk * NC + col] += acc2[mt][nt][r] * g;
      }
    }
  }
}

// ============================================================
extern "C" void kernel_launch(void* const* d_in, const int* in_sizes, int n_in,
                              void* d_out, int out_size, void* d_ws, size_t ws_size,
                              hipStream_t stream) {
  const float* x   = (const float*)d_in[0];
  const int*   aid = (const int*)d_in[1];
  const float* ln1g = (const float*)d_in[2];
  const float* ln1b = (const float*)d_in[3];
  const float* ln2g = (const float*)d_in[4];
  const float* ln2b = (const float*)d_in[5];
  const float* Wq = (const float*)d_in[6];
  const float* Aq = (const float*)d_in[7];
  const float* Bq = (const float*)d_in[8];
  const float* Wk = (const float*)d_in[9];
  const float* Ak = (const float*)d_in[10];
  const float* Bk = (const float*)d_in[11];
  const float* Wv = (const float*)d_in[12];
  const float* Av = (const float*)d_in[13];
  const float* Bv = (const float*)d_in[14];
  const float* Wo = (const float*)d_in[15];
  const float* Ao = (const float*)d_in[16];
  const float* Bo = (const float*)d_in[17];
  const float* Wr = (const float*)d_in[18];
  const float* br = (const float*)d_in[19];
  const float* W1 = (const float*)d_in[20];
  const float* A1 = (const float*)d_in[21];
  const float* B1 = (const float*)d_in[22];
  const float* W2 = (const float*)d_in[23];
  const float* A2 = (const float*)d_in[24];
  const float* B2 = (const float*)d_in[25];
  float* out = (float*)d_out;
  char* wsb = (char*)d_ws;

  unsigned short* hhi  = (unsigned short*)(wsb + OB_HSPLIT_HI);
  unsigned short* hlo  = (unsigned short*)(wsb + OB_HSPLIT_LO);
  unsigned short* ohi  = (unsigned short*)(wsb + OB_HSPLIT_HI);  // reuse after qkv
  unsigned short* olo  = (unsigned short*)(wsb + OB_HSPLIT_LO);
  unsigned short* qhi  = (unsigned short*)(wsb + OB_QHI);
  unsigned short* qlo  = (unsigned short*)(wsb + OB_QLO);
  unsigned short* khi  = (unsigned short*)(wsb + OB_KHI);
  unsigned short* klo  = (unsigned short*)(wsb + OB_KLO);
  unsigned short* vthi = (unsigned short*)(wsb + OB_VTHI);
  unsigned short* vtlo = (unsigned short*)(wsb + OB_VTLO);
  float* flat          = (float*)(wsb + OB_FLAT);
  unsigned short* wpkt_hi = (unsigned short*)(wsb + OB_WPKT_HI);
  unsigned short* wpkt_lo = (unsigned short*)(wsb + OB_WPKT_LO);
  unsigned short* woet_hi = (unsigned short*)(wsb + OB_WOET_HI);
  unsigned short* woet_lo = (unsigned short*)(wsb + OB_WOET_LO);
  unsigned short* W1T  = (unsigned short*)(wsb + OB_W1T);
  unsigned short* W2T  = (unsigned short*)(wsb + OB_W2T);
  float* probs         = (float*)(wsb + OB_PROBS);
  float* t1v           = (float*)(wsb + OB_T1V);
  int*   t1i           = (int*)(wsb + OB_T1I);
  int*   slot          = (int*)(wsb + OB_SLOT);

  pack_attn_kernel<<<1440, 256, 0, stream>>>(aid, Wq, Aq, Bq, Wk, Ak, Bk, Wv, Av, Bv,
                                             Wo, Ao, Bo, wpkt_hi, wpkt_lo, woet_hi, woet_lo, slot);
  pack_w1t_kernel<<<dim3(24, 6, 4), 256, 0, stream>>>(aid, W1, A1, B1, W1T);
  pack_w2t_kernel<<<dim3(24, 6, 4), 256, 0, stream>>>(aid, W2, A2, B2, W2T);
  ln_split_kernel<<<NTOKENS / 4, 256, 0, stream>>>(x, ln1g, ln1b, hhi, hlo);
  qkv_mfma_kernel<<<NTOKENS / 16, 256, 0, stream>>>(hhi, hlo, wpkt_hi, wpkt_lo,
                                                    qhi, qlo, khi, klo, vthi, vtlo);
  attn_mfma_kernel<<<dim3(32, 32), 128, 0, stream>>>(qhi, qlo, khi, klo, vthi, vtlo, ohi, olo);
  proj_mfma_kernel<<<NTOKENS / 16, 256, 0, stream>>>(ohi, olo, woet_hi, woet_lo, x, out);
  ln_kernel<<<NTOKENS / 4, 256, 0, stream>>>(out, ln2g, ln2b, flat);
  router_kernel<<<NTOKENS / 4, 256, 0, stream>>>(flat, Wr, br, probs, t1v, t1i);
  scan_kernel<<<1, 256, 0, stream>>>(t1i, probs, slot, out + (size_t)NTOKENS * NC);
  ffn_mfma_kernel<<<dim3(NCAP / 32, NEXP), 256, 0, stream>>>(flat, slot, t1v, W1T, W2T, out);
}

// Round 7
// 627.842 us; speedup vs baseline: 3.7333x; 1.1053x over previous
//
#include <hip/hip_runtime.h>
#include <math.h>

// ---- problem constants ----
#define NC   384
#define NHQ  8
#define NHKV 2
#define NR   4
#define NEXP 4
#define NB   4
#define NT   2048
#define NTOKENS 8192
#define NCAP 2560
#define NFF  1536
#define NQKV 576
#define LORA_SCALE 0.25f
#define L2E 1.4426950408889634f
#define QSCALE 0.14433756729740643f

// ---- ws layout (byte offsets) ----
// region [0, 31457280): hhi/hlo -> q/k/v splits -> ohi/olo -> (after proj) h1
#define OB_HSPLIT_HI ((size_t)0)
#define OB_HSPLIT_LO ((size_t)6291456)
#define OB_QHI       ((size_t)12582912)
#define OB_QLO       ((size_t)18874368)
#define OB_KHI       ((size_t)25165824)
#define OB_KLO       ((size_t)26738688)
#define OB_VTHI      ((size_t)28311552)
#define OB_VTLO      ((size_t)29884416)
#define OB_H1        ((size_t)0)             // 10240*1536*2 = 31457280 B, after proj
#define OB_FLAT      ((size_t)31457280)
#define OB_WPKT_HI   ((size_t)44040192)
#define OB_WPKT_LO   ((size_t)44482560)
#define OB_WOET_HI   ((size_t)44924928)
#define OB_WOET_LO   ((size_t)45219840)
#define OB_W1T       ((size_t)45514752)
#define OB_W2T       ((size_t)50233344)
#define OB_PROBS     ((size_t)54951936)
#define OB_T1V       ((size_t)55083008)
#define OB_T1I       ((size_t)55115776)
#define OB_SLOT      ((size_t)55148544)

typedef short bf16x8 __attribute__((ext_vector_type(8)));
typedef float f32x4  __attribute__((ext_vector_type(4)));

__device__ __forceinline__ unsigned short f2bf(float x) {
  union { float f; unsigned u; } a; a.f = x;
  unsigned r = a.u + 0x7FFFu + ((a.u >> 16) & 1u);
  return (unsigned short)(r >> 16);
}
__device__ __forceinline__ float bf2f(unsigned short h) {
  union { unsigned u; float f; } a; a.u = ((unsigned)h) << 16; return a.f;
}

#define MFMA16(a, b, c) __builtin_amdgcn_mfma_f32_16x16x32_bf16((a), (b), (c), 0, 0, 0)

// ============================================================
// LayerNorm -> split bf16 hi/lo (ln1)
// ============================================================
__global__ __launch_bounds__(256) void ln_split_kernel(const float* __restrict__ x,
    const float* __restrict__ g, const float* __restrict__ bb,
    unsigned short* __restrict__ ohi, unsigned short* __restrict__ olo) {
  int row = blockIdx.x * 4 + (threadIdx.x >> 6);
  int lane = threadIdx.x & 63;
  const float* xr = x + (size_t)row * NC;
  float v0[6];
  float s = 0.f;
#pragma unroll
  for (int i = 0; i < 6; i++) { v0[i] = xr[lane + i * 64]; s += v0[i]; }
#pragma unroll
  for (int o = 32; o > 0; o >>= 1) s += __shfl_xor(s, o);
  float mean = s * (1.f / NC);
  float s2 = 0.f;
#pragma unroll
  for (int i = 0; i < 6; i++) { float d = v0[i] - mean; s2 += d * d; }
#pragma unroll
  for (int o = 32; o > 0; o >>= 1) s2 += __shfl_xor(s2, o);
  float rstd = rsqrtf(s2 * (1.f / NC) + 1e-5f);
#pragma unroll
  for (int i = 0; i < 6; i++) {
    int c = lane + i * 64;
    float val = (v0[i] - mean) * rstd * g[c] + bb[c];
    unsigned short h = f2bf(val);
    ohi[(size_t)row * NC + c] = h;
    olo[(size_t)row * NC + c] = f2bf(val - bf2f(h));
  }
}

// ============================================================
// LayerNorm -> f32 (ln2)
// ============================================================
__global__ __launch_bounds__(256) void ln_kernel(const float* __restrict__ x,
    const float* __restrict__ g, const float* __restrict__ bb,
    float* __restrict__ out) {
  int row = blockIdx.x * 4 + (threadIdx.x >> 6);
  int lane = threadIdx.x & 63;
  const float* xr = x + (size_t)row * NC;
  float v0[6];
  float s = 0.f;
#pragma unroll
  for (int i = 0; i < 6; i++) { v0[i] = xr[lane + i * 64]; s += v0[i]; }
#pragma unroll
  for (int o = 32; o > 0; o >>= 1) s += __shfl_xor(s, o);
  float mean = s * (1.f / NC);
  float s2 = 0.f;
#pragma unroll
  for (int i = 0; i < 6; i++) { float d = v0[i] - mean; s2 += d * d; }
#pragma unroll
  for (int o = 32; o > 0; o >>= 1) s2 += __shfl_xor(s2, o);
  float rstd = rsqrtf(s2 * (1.f / NC) + 1e-5f);
  float* orow = out + (size_t)row * NC;
#pragma unroll
  for (int i = 0; i < 6; i++) {
    int c = lane + i * 64;
    orow[c] = (v0[i] - mean) * rstd * g[c] + bb[c];
  }
}

// ============================================================
// Pack attn weights: fold LoRA, TRANSPOSE, split bf16 hi/lo.
// ============================================================
__global__ __launch_bounds__(256) void pack_attn_kernel(const int* __restrict__ aidp,
    const float* __restrict__ Wq, const float* __restrict__ Aq, const float* __restrict__ Bq,
    const float* __restrict__ Wk, const float* __restrict__ Ak, const float* __restrict__ Bk,
    const float* __restrict__ Wv, const float* __restrict__ Av, const float* __restrict__ Bv,
    const float* __restrict__ Wo, const float* __restrict__ Ao, const float* __restrict__ Bo,
    unsigned short* __restrict__ wpkt_hi, unsigned short* __restrict__ wpkt_lo,
    unsigned short* __restrict__ woet_hi, unsigned short* __restrict__ woet_lo,
    int* __restrict__ slot_token) {
  int aid = aidp[0];
  int idx = blockIdx.x * 256 + threadIdx.x;
  if (idx < NC * NQKV) {
    int c = idx / NQKV, col = idx % NQKV;
    float w; const float* A; const float* B; int loc;
    if (col < 384)      { w = Wq[c * 384 + col];        A = Aq; B = Bq; loc = col; }
    else if (col < 480) { w = Wk[c * 96 + (col - 384)]; A = Ak; B = Bk; loc = col - 384; }
    else                { w = Wv[c * 96 + (col - 480)]; A = Av; B = Bv; loc = col - 480; }
    float s = 0.f;
#pragma unroll
    for (int r = 0; r < 4; r++)
      s += A[((size_t)aid * 4 + r) * NC + c] * B[((size_t)(col < 384 ? aid * 384 : aid * 96) + loc) * 4 + r];
    float val = w + LORA_SCALE * s;
    unsigned short h = f2bf(val);
    size_t tix = (size_t)col * NC + c;
    wpkt_hi[tix] = h; wpkt_lo[tix] = f2bf(val - bf2f(h));
  }
  int j = idx - NC * NQKV;
  if (j >= 0 && j < NC * NC) {
    int c = j / NC, col = j % NC;
    float s = 0.f;
#pragma unroll
    for (int r = 0; r < 4; r++)
      s += Ao[((size_t)aid * 4 + r) * NC + c] * Bo[((size_t)aid * NC + col) * 4 + r];
    float val = Wo[(size_t)c * NC + col] + LORA_SCALE * s;
    unsigned short h = f2bf(val);
    size_t tix = (size_t)col * NC + c;
    woet_hi[tix] = h; woet_lo[tix] = f2bf(val - bf2f(h));
  }
  if (idx < NEXP * NCAP) slot_token[idx] = -1;
}

// ============================================================
// Pack W1 -> W1T bf16 [E][F][C] with LoRA folded
// ============================================================
__global__ __launch_bounds__(256) void pack_w1t_kernel(const int* __restrict__ aidp,
    const float* __restrict__ W1, const float* __restrict__ A1, const float* __restrict__ B1,
    unsigned short* __restrict__ W1T) {
  __shared__ float tile[64][65];
  int aid = aidp[0];
  int e = blockIdx.z, cb = blockIdx.y, fb = blockIdx.x;
  int tid = threadIdx.x;
  int tlo = tid & 63, thi = tid >> 6;
  size_t la = ((size_t)e * 4 + aid);
#pragma unroll
  for (int ii = 0; ii < 16; ii++) {
    int c = cb * 64 + ii * 4 + thi;
    int f = fb * 64 + tlo;
    float val = W1[((size_t)e * NC + c) * NFF + f];
    float s = 0.f;
#pragma unroll
    for (int r = 0; r < 4; r++)
      s += A1[(la * 4 + r) * NC + c] * B1[(la * NFF + f) * 4 + r];
    tile[ii * 4 + thi][tlo] = val + LORA_SCALE * s;
  }
  __syncthreads();
#pragma unroll
  for (int ii = 0; ii < 16; ii++) {
    int floc = ii * 4 + thi;
    W1T[((size_t)e * NFF + fb * 64 + floc) * NC + cb * 64 + tlo] = f2bf(tile[tlo][floc]);
  }
}

// ============================================================
// Pack W2 -> W2T bf16 [E][C][F] with LoRA folded
// ============================================================
__global__ __launch_bounds__(256) void pack_w2t_kernel(const int* __restrict__ aidp,
    const float* __restrict__ W2, const float* __restrict__ A2, const float* __restrict__ B2,
    unsigned short* __restrict__ W2T) {
  __shared__ float tile[64][65];
  int aid = aidp[0];
  int e = blockIdx.z, cb = blockIdx.y, fb = blockIdx.x;
  int tid = threadIdx.x;
  int tlo = tid & 63, thi = tid >> 6;
  size_t la = ((size_t)e * 4 + aid);
#pragma unroll
  for (int ii = 0; ii < 16; ii++) {
    int f = fb * 64 + ii * 4 + thi;
    int c = cb * 64 + tlo;
    float val = W2[((size_t)e * NFF + f) * NC + c];
    float s = 0.f;
#pragma unroll
    for (int r = 0; r < 4; r++)
      s += A2[(la * 4 + r) * NFF + f] * B2[(la * NC + c) * 4 + r];
    tile[ii * 4 + thi][tlo] = val + LORA_SCALE * s;
  }
  __syncthreads();
#pragma unroll
  for (int ii = 0; ii < 16; ii++) {
    int cloc = ii * 4 + thi;
    W2T[((size_t)e * NC + cb * 64 + cloc) * NFF + fb * 64 + tlo] = f2bf(tile[tlo][cloc]);
  }
}

// ============================================================
// QKV split-bf16 MFMA GEMM with fused RoPE+scale+split epilogue
// ============================================================
__global__ __launch_bounds__(256) void qkv_mfma_kernel(
    const unsigned short* __restrict__ hhi, const unsigned short* __restrict__ hlo,
    const unsigned short* __restrict__ wthi, const unsigned short* __restrict__ wtlo,
    unsigned short* __restrict__ qhi, unsigned short* __restrict__ qlo,
    unsigned short* __restrict__ khi, unsigned short* __restrict__ klo,
    unsigned short* __restrict__ vthi, unsigned short* __restrict__ vtlo) {
  const int m0 = blockIdx.x * 16;
  const int tid = threadIdx.x;
  const int w = tid >> 6, lane = tid & 63;
  const int lq = lane & 15, g = lane >> 4;
  bf16x8 ah[12], al[12];
  const unsigned short* arow_h = hhi + (size_t)(m0 + lq) * NC;
  const unsigned short* arow_l = hlo + (size_t)(m0 + lq) * NC;
#pragma unroll
  for (int kk = 0; kk < 12; kk++) {
    ah[kk] = *(const bf16x8*)(arow_h + kk * 32 + g * 8);
    al[kk] = *(const bf16x8*)(arow_l + kk * 32 + g * 8);
  }
#pragma unroll
  for (int nt = 0; nt < 9; nt++) {
    const int ncol = w * 144 + nt * 16 + lq;
    const int colbase = w * 144 + nt * 16;
    const unsigned short* bp_h = wthi + (size_t)ncol * NC;
    const unsigned short* bp_l = wtlo + (size_t)ncol * NC;
    f32x4 c = (f32x4){0.f, 0.f, 0.f, 0.f};
#pragma unroll
    for (int kk = 0; kk < 12; kk++) {
      bf16x8 bh = *(const bf16x8*)(bp_h + kk * 32 + g * 8);
      bf16x8 bl = *(const bf16x8*)(bp_l + kk * 32 + g * 8);
      c = MFMA16(ah[kk], bh, c);
      c = MFMA16(al[kk], bh, c);
      c = MFMA16(ah[kk], bl, c);
    }
    if (colbase < 480) {                       // q or k: rope
      const int dloc = ncol % 48;
      const int j = dloc >> 1;
      const int parity = ncol & 1;
      const bool isq = colbase < 384;
      const float scale = isq ? QSCALE : 1.f;
      const float inv = powf(10000.f, -(float)(2 * j) * (1.f / 48.f));
#pragma unroll
      for (int r = 0; r < 4; r++) {
        int row = m0 + g * 4 + r;
        int t = row & (NT - 1);
        int bb = row >> 11;
        float sn, cs; sincosf((float)t * inv, &sn, &cs);
        float pv = __shfl_xor(c[r], 1);
        float roped = (c[r] * cs + (parity ? pv * sn : -pv * sn)) * scale;
        unsigned short h_ = f2bf(roped);
        unsigned short l_ = f2bf(roped - bf2f(h_));
        size_t idx;
        if (isq) {
          idx = ((size_t)(bb * NHQ + ncol / 48) * NT + t) * 48 + dloc;
          qhi[idx] = h_; qlo[idx] = l_;
        } else {
          int ck = ncol - 384;
          idx = ((size_t)(bb * NHKV + ck / 48) * NT + t) * 48 + (ck % 48);
          khi[idx] = h_; klo[idx] = l_;
        }
      }
    } else {                                   // v: transpose store
      const int cv = ncol - 480;
      const int hh = cv / 48, dloc = cv % 48;
#pragma unroll
      for (int r = 0; r < 4; r++) {
        int row = m0 + g * 4 + r;
        int t = row & (NT - 1);
        int bb = row >> 11;
        float val = c[r];
        unsigned short h_ = f2bf(val);
        unsigned short l_ = f2bf(val - bf2f(h_));
        size_t idx = ((size_t)(bb * NHKV + hh) * 48 + dloc) * NT + t;
        vthi[idx] = h_; vtlo[idx] = l_;
      }
    }
  }
}

// ============================================================
// Flash attention, split-bf16 MFMA, no K/V LDS staging.
// ============================================================
__global__ __launch_bounds__(128) void attn_mfma_kernel(
    const unsigned short* __restrict__ qhi, const unsigned short* __restrict__ qlo,
    const unsigned short* __restrict__ khi, const unsigned short* __restrict__ klo,
    const unsigned short* __restrict__ vthi, const unsigned short* __restrict__ vtlo,
    unsigned short* __restrict__ ohi, unsigned short* __restrict__ olo) {
  __shared__ unsigned short Pt[2][4096];
  const int qb = 31 - (int)blockIdx.x;
  const int bh = blockIdx.y;
  const int b = bh >> 3, hq = bh & 7, hk = hq >> 2;
  const int bhk = b * NHKV + hk;
  const int tid = threadIdx.x;
  const int w = tid >> 6, lane = tid & 63;
  const int lq = lane & 15, g = lane >> 4;
  const int sw = lq & 7;
  unsigned short* PtW = Pt[w];
  const bf16x8 zf = {0, 0, 0, 0, 0, 0, 0, 0};

  bf16x8 qfh[2][2], qfl[2][2];
#pragma unroll
  for (int qs = 0; qs < 2; qs++) {
    size_t qoff = ((size_t)bh * NT + qb * 64 + w * 32 + qs * 16 + lq) * 48;
    qfh[qs][0] = *(const bf16x8*)(qhi + qoff + g * 8);
    qfl[qs][0] = *(const bf16x8*)(qlo + qoff + g * 8);
    qfh[qs][1] = (g < 2) ? *(const bf16x8*)(qhi + qoff + 32 + g * 8) : zf;
    qfl[qs][1] = (g < 2) ? *(const bf16x8*)(qlo + qoff + 32 + g * 8) : zf;
  }
  f32x4 acc[2][3];
#pragma unroll
  for (int qs = 0; qs < 2; qs++)
#pragma unroll
    for (int dt = 0; dt < 3; dt++) acc[qs][dt] = (f32x4){0.f, 0.f, 0.f, 0.f};
  float m[2] = {-1e30f, -1e30f}, l[2] = {0.f, 0.f};

  const unsigned short* kb_h = khi + (size_t)bhk * NT * 48;
  const unsigned short* kb_l = klo + (size_t)bhk * NT * 48;
  const unsigned short* vb_h = vthi + (size_t)bhk * 48 * NT;
  const unsigned short* vb_l = vtlo + (size_t)bhk * 48 * NT;

  for (int kt = 0; kt <= qb; kt++) {
    f32x4 s[2][4];
#pragma unroll
    for (int qs = 0; qs < 2; qs++)
#pragma unroll
      for (int ct = 0; ct < 4; ct++) s[qs][ct] = (f32x4){0.f, 0.f, 0.f, 0.f};
#pragma unroll
    for (int ct = 0; ct < 4; ct++) {
      const size_t ko = (size_t)(kt * 64 + ct * 16 + lq) * 48;
      bf16x8 kh0 = *(const bf16x8*)(kb_h + ko + g * 8);
      bf16x8 kl0 = *(const bf16x8*)(kb_l + ko + g * 8);
      bf16x8 kh1 = (g < 2) ? *(const bf16x8*)(kb_h + ko + 32 + g * 8) : zf;
      bf16x8 kl1 = (g < 2) ? *(const bf16x8*)(kb_l + ko + 32 + g * 8) : zf;
#pragma unroll
      for (int qs = 0; qs < 2; qs++) {
        s[qs][ct] = MFMA16(kh0, qfh[qs][0], s[qs][ct]);
        s[qs][ct] = MFMA16(kl0, qfh[qs][0], s[qs][ct]);
        s[qs][ct] = MFMA16(kh0, qfl[qs][0], s[qs][ct]);
        s[qs][ct] = MFMA16(kh1, qfh[qs][1], s[qs][ct]);
        s[qs][ct] = MFMA16(kl1, qfh[qs][1], s[qs][ct]);
        s[qs][ct] = MFMA16(kh1, qfl[qs][1], s[qs][ct]);
      }
    }
    if (kt == qb) {
#pragma unroll
      for (int qs = 0; qs < 2; qs++) {
        const int qg = qb * 64 + w * 32 + qs * 16 + lq;
#pragma unroll
        for (int ct = 0; ct < 4; ct++) {
          const int k0 = kt * 64 + ct * 16 + g * 4;
#pragma unroll
          for (int r = 0; r < 4; r++)
            if (k0 + r > qg) s[qs][ct][r] = -1e30f;
        }
      }
    }
#pragma unroll
    for (int qs = 0; qs < 2; qs++) {
      float mx = s[qs][0][0];
#pragma unroll
      for (int ct = 0; ct < 4; ct++)
#pragma unroll
        for (int r = 0; r < 4; r++) mx = fmaxf(mx, s[qs][ct][r]);
      mx = fmaxf(mx, __shfl_xor(mx, 16));
      mx = fmaxf(mx, __shfl_xor(mx, 32));
      const float mnew = fmaxf(m[qs], mx);
      const float corr = exp2f((m[qs] - mnew) * L2E);
      m[qs] = mnew;
      float ps = 0.f;
      unsigned short* prow = PtW + (qs * 16 + lq) * 128;
#pragma unroll
      for (int ct = 0; ct < 4; ct++) {
        float p0 = exp2f((s[qs][ct][0] - mnew) * L2E);
        float p1 = exp2f((s[qs][ct][1] - mnew) * L2E);
        float p2 = exp2f((s[qs][ct][2] - mnew) * L2E);
        float p3 = exp2f((s[qs][ct][3] - mnew) * L2E);
        ps += (p0 + p1) + (p2 + p3);
        unsigned short h0 = f2bf(p0), h1 = f2bf(p1), h2 = f2bf(p2), h3 = f2bf(p3);
        unsigned short l0 = f2bf(p0 - bf2f(h0)), l1 = f2bf(p1 - bf2f(h1));
        unsigned short l2 = f2bf(p2 - bf2f(h2)), l3 = f2bf(p3 - bf2f(h3));
        uint2 wh, wl;
        wh.x = (unsigned)h0 | ((unsigned)h1 << 16); wh.y = (unsigned)h2 | ((unsigned)h3 << 16);
        wl.x = (unsigned)l0 | ((unsigned)l1 << 16); wl.y = (unsigned)l2 | ((unsigned)l3 << 16);
        const int u = ct * 2 + (g >> 1), sub = (g & 1) * 4;
        *(uint2*)&prow[((u ^ sw) << 3) + sub] = wh;
        *(uint2*)&prow[(((8 + u) ^ sw) << 3) + sub] = wl;
      }
      ps += __shfl_xor(ps, 16);
      ps += __shfl_xor(ps, 32);
      l[qs] = l[qs] * corr + ps;
#pragma unroll
      for (int dt = 0; dt < 3; dt++) acc[qs][dt] *= corr;
    }
    bf16x8 pfh[2][2], pfl[2][2];
#pragma unroll
    for (int qs = 0; qs < 2; qs++) {
      const unsigned short* prow = PtW + (qs * 16 + lq) * 128;
#pragma unroll
      for (int c = 0; c < 2; c++) {
        pfh[qs][c] = *(const bf16x8*)&prow[((c * 4 + g) ^ sw) << 3];
        pfl[qs][c] = *(const bf16x8*)&prow[((8 + c * 4 + g) ^ sw) << 3];
      }
    }
#pragma unroll
    for (int dt = 0; dt < 3; dt++) {
      const size_t vo = (size_t)(dt * 16 + lq) * NT + kt * 64;
      bf16x8 vh0 = *(const bf16x8*)(vb_h + vo + g * 8);
      bf16x8 vl0 = *(const bf16x8*)(vb_l + vo + g * 8);
      bf16x8 vh1 = *(const bf16x8*)(vb_h + vo + 32 + g * 8);
      bf16x8 vl1 = *(const bf16x8*)(vb_l + vo + 32 + g * 8);
#pragma unroll
      for (int qs = 0; qs < 2; qs++) {
        acc[qs][dt] = MFMA16(vh0, pfh[qs][0], acc[qs][dt]);
        acc[qs][dt] = MFMA16(vl0, pfh[qs][0], acc[qs][dt]);
        acc[qs][dt] = MFMA16(vh0, pfl[qs][0], acc[qs][dt]);
        acc[qs][dt] = MFMA16(vh1, pfh[qs][1], acc[qs][dt]);
        acc[qs][dt] = MFMA16(vl1, pfh[qs][1], acc[qs][dt]);
        acc[qs][dt] = MFMA16(vh1, pfl[qs][1], acc[qs][dt]);
      }
    }
  }
#pragma unroll
  for (int qs = 0; qs < 2; qs++) {
    const float invl = 1.f / l[qs];
    const int qg = qb * 64 + w * 32 + qs * 16 + lq;
    const size_t base = ((size_t)b * NT + qg) * NC + hq * 48 + g * 4;
#pragma unroll
    for (int dt = 0; dt < 3; dt++) {
      unsigned short h4[4], l4[4];
#pragma unroll
      for (int r = 0; r < 4; r++) {
        float v = acc[qs][dt][r] * invl;
        h4[r] = f2bf(v);
        l4[r] = f2bf(v - bf2f(h4[r]));
      }
      uint2 wh, wl;
      wh.x = (unsigned)h4[0] | ((unsigned)h4[1] << 16); wh.y = (unsigned)h4[2] | ((unsigned)h4[3] << 16);
      wl.x = (unsigned)l4[0] | ((unsigned)l4[1] << 16); wl.y = (unsigned)l4[2] | ((unsigned)l4[3] << 16);
      *(uint2*)(ohi + base + dt * 16) = wh;
      *(uint2*)(olo + base + dt * 16) = wl;
    }
  }
}

// ============================================================
// O-projection split-bf16 MFMA + residual
// ============================================================
__global__ __launch_bounds__(256) void proj_mfma_kernel(
    const unsigned short* __restrict__ ohi, const unsigned short* __restrict__ olo,
    const unsigned short* __restrict__ wthi, const unsigned short* __restrict__ wtlo,
    const float* __restrict__ x, float* __restrict__ out) {
  const int m0 = blockIdx.x * 16;
  const int tid = threadIdx.x;
  const int w = tid >> 6, lane = tid & 63;
  const int lq = lane & 15, g = lane >> 4;
  bf16x8 ah[12], al[12];
  const unsigned short* arow_h = ohi + (size_t)(m0 + lq) * NC;
  const unsigned short* arow_l = olo + (size_t)(m0 + lq) * NC;
#pragma unroll
  for (int kk = 0; kk < 12; kk++) {
    ah[kk] = *(const bf16x8*)(arow_h + kk * 32 + g * 8);
    al[kk] = *(const bf16x8*)(arow_l + kk * 32 + g * 8);
  }
#pragma unroll
  for (int nt = 0; nt < 6; nt++) {
    const int ncol = w * 96 + nt * 16 + lq;
    const unsigned short* bp_h = wthi + (size_t)ncol * NC;
    const unsigned short* bp_l = wtlo + (size_t)ncol * NC;
    f32x4 c = (f32x4){0.f, 0.f, 0.f, 0.f};
#pragma unroll
    for (int kk = 0; kk < 12; kk++) {
      bf16x8 bh = *(const bf16x8*)(bp_h + kk * 32 + g * 8);
      bf16x8 bl = *(const bf16x8*)(bp_l + kk * 32 + g * 8);
      c = MFMA16(ah[kk], bh, c);
      c = MFMA16(al[kk], bh, c);
      c = MFMA16(ah[kk], bl, c);
    }
#pragma unroll
    for (int r = 0; r < 4; r++) {
      size_t row = m0 + g * 4 + r;
      out[row * NC + ncol] = x[row * NC + ncol] + c[r];
    }
  }
}

// ============================================================
// Router: wave per token
// ============================================================
__global__ __launch_bounds__(256) void router_kernel(const float* __restrict__ flat,
    const float* __restrict__ Wr, const float* __restrict__ br,
    float* __restrict__ probs, float* __restrict__ top1_val, int* __restrict__ top1_idx) {
  int tid = threadIdx.x;
  int lane = tid & 63, w = tid >> 6;
  int token = blockIdx.x * 4 + w;
  const float* fr = flat + (size_t)token * NC;
  float p0 = 0.f, p1 = 0.f, p2 = 0.f, p3 = 0.f;
  for (int c = lane; c < NC; c += 64) {
    float f = fr[c];
    const float4 wr = *(const float4*)(Wr + c * 4);
    p0 += f * wr.x; p1 += f * wr.y; p2 += f * wr.z; p3 += f * wr.w;
  }
#pragma unroll
  for (int off = 32; off > 0; off >>= 1) {
    p0 += __shfl_xor(p0, off); p1 += __shfl_xor(p1, off);
    p2 += __shfl_xor(p2, off); p3 += __shfl_xor(p3, off);
  }
  if (lane == 0) {
    float l0 = p0 + br[0], l1 = p1 + br[1], l2 = p2 + br[2], l3 = p3 + br[3];
    float mx = fmaxf(fmaxf(l0, l1), fmaxf(l2, l3));
    float e0 = expf(l0 - mx), e1 = expf(l1 - mx), e2 = expf(l2 - mx), e3 = expf(l3 - mx);
    float inv = 1.f / (e0 + e1 + e2 + e3);
    float q0 = e0 * inv, q1 = e1 * inv, q2 = e2 * inv, q3 = e3 * inv;
    probs[token * 4 + 0] = q0; probs[token * 4 + 1] = q1;
    probs[token * 4 + 2] = q2; probs[token * 4 + 3] = q3;
    int best = 0; float bv = q0;
    if (q1 > bv) { bv = q1; best = 1; }
    if (q2 > bv) { bv = q2; best = 2; }
    if (q3 > bv) { bv = q3; best = 3; }
    top1_idx[token] = best;
    top1_val[token] = bv;
  }
}

// ============================================================
// Scan: deterministic rank within expert, slot list, aux
// ============================================================
__global__ __launch_bounds__(256) void scan_kernel(const int* __restrict__ top1_idx,
    const float* __restrict__ probs, int* __restrict__ slot_token,
    float* __restrict__ aux_out) {
  __shared__ float psums[4];
  __shared__ int cnts[4][256];
  __shared__ int tot[4];
  int tid = threadIdx.x;
  int base = tid * 32;
  float s0 = 0.f, s1 = 0.f, s2 = 0.f, s3 = 0.f;
  int c0 = 0, c1 = 0, c2 = 0, c3 = 0;
  for (int i = 0; i < 32; i++) {
    int tk = base + i;
    s0 += probs[tk * 4 + 0]; s1 += probs[tk * 4 + 1];
    s2 += probs[tk * 4 + 2]; s3 += probs[tk * 4 + 3];
    int e = top1_idx[tk];
    if (e == 0) c0++; else if (e == 1) c1++; else if (e == 2) c2++; else c3++;
  }
  if (tid < 4) psums[tid] = 0.f;
  cnts[0][tid] = c0; cnts[1][tid] = c1; cnts[2][tid] = c2; cnts[3][tid] = c3;
  __syncthreads();
#pragma unroll
  for (int off = 32; off > 0; off >>= 1) {
    s0 += __shfl_xor(s0, off); s1 += __shfl_xor(s1, off);
    s2 += __shfl_xor(s2, off); s3 += __shfl_xor(s3, off);
  }
  if ((tid & 63) == 0) {
    atomicAdd(&psums[0], s0); atomicAdd(&psums[1], s1);
    atomicAdd(&psums[2], s2); atomicAdd(&psums[3], s3);
  }
  int w = tid >> 6, lane = tid & 63;
  int v0 = cnts[w][lane * 4 + 0], v1 = cnts[w][lane * 4 + 1];
  int v2 = cnts[w][lane * 4 + 2], v3 = cnts[w][lane * 4 + 3];
  int t4 = v0 + v1 + v2 + v3;
  int incl = t4;
#pragma unroll
  for (int off = 1; off < 64; off <<= 1) {
    int n = __shfl_up(incl, off);
    if (lane >= off) incl += n;
  }
  int excl = incl - t4;
  __syncthreads();
  cnts[w][lane * 4 + 0] = excl;
  cnts[w][lane * 4 + 1] = excl + v0;
  cnts[w][lane * 4 + 2] = excl + v0 + v1;
  cnts[w][lane * 4 + 3] = excl + v0 + v1 + v2;
  if (lane == 63) tot[w] = incl;
  __syncthreads();
  int pe0 = cnts[0][tid], pe1 = cnts[1][tid], pe2 = cnts[2][tid], pe3 = cnts[3][tid];
  for (int i = 0; i < 32; i++) {
    int tk = base + i;
    int e = top1_idx[tk];
    int r;
    if (e == 0) r = pe0++;
    else if (e == 1) r = pe1++;
    else if (e == 2) r = pe2++;
    else r = pe3++;
    if (r < NCAP) slot_token[e * NCAP + r] = tk;
  }
  __syncthreads();
  if (tid == 0) {
    float aux = 0.f;
#pragma unroll
    for (int e = 0; e < 4; e++) {
      int d = tot[e] < NCAP ? tot[e] : NCAP;
      aux += (psums[e] * (1.f / NTOKENS)) * ((float)d * (1.f / NTOKENS));
    }
    aux_out[0] = aux * (float)NEXP;
  }
}

// ============================================================
// FFN stage 1: h1 = relu(ft @ W1T) bf16.
// grid (NCAP/32, NFF/256, E), 256 thr. Wave w: 64 cols.
// B-frag feeds 2 MFMAs (a[2][12] in regs).
// ============================================================
__global__ __launch_bounds__(256) void ffn1_kernel(const float* __restrict__ flat,
    const int* __restrict__ slot_token,
    const unsigned short* __restrict__ W1T,
    unsigned short* __restrict__ h1) {
  __shared__ unsigned short ft[32][392];
  __shared__ int toks[32];
  const int e = blockIdx.z;
  const int n0 = blockIdx.y * 256;
  const int s0 = blockIdx.x * 32;
  const int tid = threadIdx.x;
  const int w = tid >> 6, lane = tid & 63;
  const int lq = lane & 15, kgrp = lane >> 4;
  if (tid < 32) toks[tid] = slot_token[e * NCAP + s0 + tid];
  __syncthreads();
  if (toks[0] < 0) return;
  for (int i = tid; i < 32 * 384; i += 256) {
    int r = i / 384, c = i - r * 384;
    int tk = toks[r];
    float xv = (tk >= 0) ? flat[(size_t)tk * NC + c] : 0.f;
    ft[r][c] = f2bf(xv);
  }
  __syncthreads();
  bf16x8 a[2][12];
#pragma unroll
  for (int mt = 0; mt < 2; mt++)
#pragma unroll
    for (int kk = 0; kk < 12; kk++)
      a[mt][kk] = *(const bf16x8*)&ft[mt * 16 + lq][kk * 32 + kgrp * 8];
#pragma unroll
  for (int nt = 0; nt < 4; nt++) {
    const int ncol = n0 + w * 64 + nt * 16 + lq;
    const unsigned short* bp = W1T + ((size_t)e * NFF + ncol) * NC;
    f32x4 c0 = (f32x4){0.f, 0.f, 0.f, 0.f};
    f32x4 c1 = (f32x4){0.f, 0.f, 0.f, 0.f};
#pragma unroll
    for (int kk = 0; kk < 12; kk++) {
      bf16x8 bf = *(const bf16x8*)(bp + kk * 32 + kgrp * 8);
      c0 = MFMA16(a[0][kk], bf, c0);
      c1 = MFMA16(a[1][kk], bf, c1);
    }
    unsigned short* hp0 = h1 + ((size_t)(e * NCAP + s0 + kgrp * 4)) * NFF + ncol;
    unsigned short* hp1 = hp0 + (size_t)16 * NFF;
#pragma unroll
    for (int r = 0; r < 4; r++) {
      hp0[(size_t)r * NFF] = f2bf(fmaxf(c0[r], 0.f));
      hp1[(size_t)r * NFF] = f2bf(fmaxf(c1[r], 0.f));
    }
  }
}

// ============================================================
// FFN stage 2: out[tk] += (h1 @ W2T) * gate.
// grid (NCAP/32, 2, E), 256 thr. No LDS staging; A from L2 h1,
// B feeds 2 MFMAs, A feeds 3.
// ============================================================
__global__ __launch_bounds__(256) void ffn2_kernel(
    const int* __restrict__ slot_token, const float* __restrict__ top1_val,
    const unsigned short* __restrict__ h1, const unsigned short* __restrict__ W2T,
    float* __restrict__ out) {
  __shared__ int toks[32];
  __shared__ float gates[32];
  const int e = blockIdx.z;
  const int nh = blockIdx.y;           // 0/1: cols [nh*192, nh*192+192)
  const int s0 = blockIdx.x * 32;
  const int tid = threadIdx.x;
  const int w = tid >> 6, lane = tid & 63;
  const int lq = lane & 15, kgrp = lane >> 4;
  if (tid < 32) {
    int tk = slot_token[e * NCAP + s0 + tid];
    toks[tid] = tk;
    gates[tid] = (tk >= 0) ? top1_val[tk] : 0.f;
  }
  __syncthreads();
  if (toks[0] < 0) return;
  const unsigned short* a0p = h1 + ((size_t)(e * NCAP + s0 + lq)) * NFF + kgrp * 8;
  const unsigned short* a1p = a0p + (size_t)16 * NFF;
  const int ncb = nh * 192 + w * 48;
  const unsigned short* bp0 = W2T + ((size_t)e * NC + ncb + lq) * NFF + kgrp * 8;
  const unsigned short* bp1 = bp0 + (size_t)16 * NFF;
  const unsigned short* bp2 = bp0 + (size_t)32 * NFF;
  f32x4 acc[2][3];
#pragma unroll
  for (int mt = 0; mt < 2; mt++)
#pragma unroll
    for (int nt = 0; nt < 3; nt++) acc[mt][nt] = (f32x4){0.f, 0.f, 0.f, 0.f};
#pragma unroll 8
  for (int kk = 0; kk < 48; kk++) {
    bf16x8 af0 = *(const bf16x8*)(a0p + kk * 32);
    bf16x8 af1 = *(const bf16x8*)(a1p + kk * 32);
    bf16x8 b0 = *(const bf16x8*)(bp0 + kk * 32);
    bf16x8 b1 = *(const bf16x8*)(bp1 + kk * 32);
    bf16x8 b2 = *(const bf16x8*)(bp2 + kk * 32);
    acc[0][0] = MFMA16(af0, b0, acc[0][0]);
    acc[1][0] = MFMA16(af1, b0, acc[1][0]);
    acc[0][1] = MFMA16(af0, b1, acc[0][1]);
    acc[1][1] = MFMA16(af1, b1, acc[1][1]);
    acc[0][2] = MFMA16(af0, b2, acc[0][2]);
    acc[1][2] = MFMA16(af1, b2, acc[1][2]);
  }
#pragma unroll
  for (int mt = 0; mt < 2; mt++) {
#pragma unroll
    for (int r = 0; r < 4; r++) {
      const int srow = mt * 16 + kgrp * 4 + r;
      const int tk = toks[srow];
      if (tk < 0) continue;
      const float g = gates[srow];
#pragma unroll
      for (int nt = 0; nt < 3; nt++) {
        const int col = ncb + nt * 16 + lq;
        out[(size_t)tk * NC + col] += acc[mt][nt][r] * g;
      }
    }
  }
}

// ============================================================
extern "C" void kernel_launch(void* const* d_in, const int* in_sizes, int n_in,
                              void* d_out, int out_size, void* d_ws, size_t ws_size,
                              hipStream_t stream) {
  const float* x   = (const float*)d_in[0];
  const int*   aid = (const int*)d_in[1];
  const float* ln1g = (const float*)d_in[2];
  const float* ln1b = (const float*)d_in[3];
  const float* ln2g = (const float*)d_in[4];
  const float* ln2b = (const float*)d_in[5];
  const float* Wq = (const float*)d_in[6];
  const float* Aq = (const float*)d_in[7];
  const float* Bq = (const float*)d_in[8];
  const float* Wk = (const float*)d_in[9];
  const float* Ak = (const float*)d_in[10];
  const float* Bk = (const float*)d_in[11];
  const float* Wv = (const float*)d_in[12];
  const float* Av = (const float*)d_in[13];
  const float* Bv = (const float*)d_in[14];
  const float* Wo = (const float*)d_in[15];
  const float* Ao = (const float*)d_in[16];
  const float* Bo = (const float*)d_in[17];
  const float* Wr = (const float*)d_in[18];
  const float* br = (const float*)d_in[19];
  const float* W1 = (const float*)d_in[20];
  const float* A1 = (const float*)d_in[21];
  const float* B1 = (const float*)d_in[22];
  const float* W2 = (const float*)d_in[23];
  const float* A2 = (const float*)d_in[24];
  const float* B2 = (const float*)d_in[25];
  float* out = (float*)d_out;
  char* wsb = (char*)d_ws;

  unsigned short* hhi  = (unsigned short*)(wsb + OB_HSPLIT_HI);
  unsigned short* hlo  = (unsigned short*)(wsb + OB_HSPLIT_LO);
  unsigned short* ohi  = (unsigned short*)(wsb + OB_HSPLIT_HI);
  unsigned short* olo  = (unsigned short*)(wsb + OB_HSPLIT_LO);
  unsigned short* qhi  = (unsigned short*)(wsb + OB_QHI);
  unsigned short* qlo  = (unsigned short*)(wsb + OB_QLO);
  unsigned short* khi  = (unsigned short*)(wsb + OB_KHI);
  unsigned short* klo  = (unsigned short*)(wsb + OB_KLO);
  unsigned short* vthi = (unsigned short*)(wsb + OB_VTHI);
  unsigned short* vtlo = (unsigned short*)(wsb + OB_VTLO);
  unsigned short* h1   = (unsigned short*)(wsb + OB_H1);   // after proj, region dead
  float* flat          = (float*)(wsb + OB_FLAT);
  unsigned short* wpkt_hi = (unsigned short*)(wsb + OB_WPKT_HI);
  unsigned short* wpkt_lo = (unsigned short*)(wsb + OB_WPKT_LO);
  unsigned short* woet_hi = (unsigned short*)(wsb + OB_WOET_HI);
  unsigned short* woet_lo = (unsigned short*)(wsb + OB_WOET_LO);
  unsigned short* W1T  = (unsigned short*)(wsb + OB_W1T);
  unsigned short* W2T  = (unsigned short*)(wsb + OB_W2T);
  float* probs         = (float*)(wsb + OB_PROBS);
  float* t1v           = (float*)(wsb + OB_T1V);
  int*   t1i           = (int*)(wsb + OB_T1I);
  int*   slot          = (int*)(wsb + OB_SLOT);

  pack_attn_kernel<<<1440, 256, 0, stream>>>(aid, Wq, Aq, Bq, Wk, Ak, Bk, Wv, Av, Bv,
                                             Wo, Ao, Bo, wpkt_hi, wpkt_lo, woet_hi, woet_lo, slot);
  pack_w1t_kernel<<<dim3(24, 6, 4), 256, 0, stream>>>(aid, W1, A1, B1, W1T);
  pack_w2t_kernel<<<dim3(24, 6, 4), 256, 0, stream>>>(aid, W2, A2, B2, W2T);
  ln_split_kernel<<<NTOKENS / 4, 256, 0, stream>>>(x, ln1g, ln1b, hhi, hlo);
  qkv_mfma_kernel<<<NTOKENS / 16, 256, 0, stream>>>(hhi, hlo, wpkt_hi, wpkt_lo,
                                                    qhi, qlo, khi, klo, vthi, vtlo);
  attn_mfma_kernel<<<dim3(32, 32), 128, 0, stream>>>(qhi, qlo, khi, klo, vthi, vtlo, ohi, olo);
  proj_mfma_kernel<<<NTOKENS / 16, 256, 0, stream>>>(ohi, olo, woet_hi, woet_lo, x, out);
  ln_kernel<<<NTOKENS / 4, 256, 0, stream>>>(out, ln2g, ln2b, flat);
  router_kernel<<<NTOKENS / 4, 256, 0, stream>>>(flat, Wr, br, probs, t1v, t1i);
  scan_kernel<<<1, 256, 0, stream>>>(t1i, probs, slot, out + (size_t)NTOKENS * NC);
  ffn1_kernel<<<dim3(NCAP / 32, NFF / 256, NEXP), 256, 0, stream>>>(flat, slot, W1T, h1);
  ffn2_kernel<<<dim3(NCAP / 32, 2, NEXP), 256, 0, stream>>>(slot, t1v, h1, W2T, out);
}